// Round 1
// baseline (3933.207 us; speedup 1.0000x reference)
//
#include <hip/hip_runtime.h>
#include <cstdio>

#define DD 128
#define NREL 4

struct Ptr4 { const float* p[4]; };
struct Out4 { float* p[4]; };

// processing-order relation r uses edge_index/rel_emb row (r+3)&3  (perm = [3,0,1,2])
__device__ __forceinline__ int edge_perm(int r) { return (r + 3) & 3; }

// ---------------- init ----------------

__global__ void init_embs(const float* __restrict__ feat, float* __restrict__ embs, size_t NK) {
  size_t i = (size_t)blockIdx.x * 256 + threadIdx.x;
  if (i < NK) {
    float v = feat[i];
    embs[i] = v; embs[NK + i] = v; embs[2 * NK + i] = v; embs[3 * NK + i] = v;
  }
}

__global__ void rels_init(const float* __restrict__ rel_emb, float* __restrict__ rels) {
  int t = threadIdx.x;              // 512 = r*128 + c
  int r = t >> 7, c = t & 127;
  rels[t] = rel_emb[edge_perm(r) * DD + c];
}

// wt[z][c][j] = W_z[j][c]; z: 0=q 1=k 2=v 3=out 4=fusion
__global__ void transpose_w(const float* __restrict__ w_in, const float* __restrict__ w_out,
                            const float* __restrict__ w_fus, float* __restrict__ wt) {
  int i = blockIdx.x * 256 + threadIdx.x;   // 5*16384
  int z = i >> 14, rem = i & 16383;
  int c = rem >> 7, j = rem & 127;
  float v;
  if (z < 3) v = w_in[(z * DD + j) * DD + c];
  else if (z == 3) v = w_out[j * DD + c];
  else v = w_fus[j * DD + c];
  wt[i] = v;
}

__global__ void count_deg(const int* __restrict__ ei, float* __restrict__ deg, int N, int E) {
  int r = blockIdx.y;
  int e = blockIdx.x * 256 + threadIdx.x;
  if (e < E) {
    int dst = ei[(size_t)edge_perm(r) * 2 * E + E + e];
    atomicAdd(deg + (size_t)r * N + dst, 1.0f);
  }
}

__global__ void finalize_dinv(float* __restrict__ deg, int total) {
  int i = blockIdx.x * 256 + threadIdx.x;
  if (i < total) deg[i] = rsqrtf(deg[i] + 1.0f);
}

// Ws[r][c][j] = rels[r][c] * Wg[c][j]   (fold column scale into weight)
__global__ void scale_w(const float* __restrict__ rels_i, const float* __restrict__ Wg,
                        float* __restrict__ Ws) {
  int i = blockIdx.x * 256 + threadIdx.x;   // 4*16384
  int r = i >> 14, rem = i & 16383, c = rem >> 7;
  Ws[i] = rels_i[r * DD + c] * Wg[rem];
}

// ---------------- GEMM: Y[M,128] = X[M,128] @ W[128,128] (+bias) , z-batched x4 ----------------
__global__ __launch_bounds__(256) void gemm4(Ptr4 xs, Ptr4 wz, Out4 ys,
                                             const float* __restrict__ bias, int M) {
  int z = blockIdx.y;
  const float* __restrict__ X = xs.p[z];
  const float* __restrict__ W = wz.p[z];
  float* __restrict__ Y = ys.p[z];
  int row0 = blockIdx.x * 64;
  __shared__ float Xs[64][132];             // +4 pad: conflict-free column reads
  int tid = threadIdx.x;
#pragma unroll
  for (int it = 0; it < 8; ++it) {
    int idx = it * 256 + tid;               // float4 id 0..2047
    int rr = idx >> 5, cc = (idx & 31) * 4;
    float4 v = make_float4(0.f, 0.f, 0.f, 0.f);
    if (row0 + rr < M) v = *(const float4*)(X + (size_t)(row0 + rr) * DD + cc);
    *(float4*)(&Xs[rr][cc]) = v;
  }
  __syncthreads();
  int tx = tid & 15, ty = tid >> 4;         // cols tx*8..+7, rows ty*4..+3
  float acc[4][8];
#pragma unroll
  for (int i = 0; i < 4; ++i)
#pragma unroll
    for (int j = 0; j < 8; ++j) acc[i][j] = 0.f;
  const float* Wp = W + tx * 8;
#pragma unroll 4
  for (int kk = 0; kk < 128; ++kk) {
    float4 w0 = *(const float4*)(Wp + kk * DD);
    float4 w1 = *(const float4*)(Wp + kk * DD + 4);
#pragma unroll
    for (int i = 0; i < 4; ++i) {
      float xv = Xs[ty * 4 + i][kk];
      acc[i][0] += xv * w0.x; acc[i][1] += xv * w0.y;
      acc[i][2] += xv * w0.z; acc[i][3] += xv * w0.w;
      acc[i][4] += xv * w1.x; acc[i][5] += xv * w1.y;
      acc[i][6] += xv * w1.z; acc[i][7] += xv * w1.w;
    }
  }
  float b0[8];
#pragma unroll
  for (int j = 0; j < 8; ++j) b0[j] = bias ? bias[tx * 8 + j] : 0.f;
#pragma unroll
  for (int i = 0; i < 4; ++i) {
    int row = row0 + ty * 4 + i;
    if (row < M) {
      float4 o0 = make_float4(acc[i][0] + b0[0], acc[i][1] + b0[1], acc[i][2] + b0[2], acc[i][3] + b0[3]);
      float4 o1 = make_float4(acc[i][4] + b0[4], acc[i][5] + b0[5], acc[i][6] + b0[6], acc[i][7] + b0[7]);
      *(float4*)(Y + (size_t)row * DD + tx * 8) = o0;
      *(float4*)(Y + (size_t)row * DD + tx * 8 + 4) = o1;
    }
  }
}

// ---------------- GCN aggregation ----------------

__global__ void scatter_edges(const int* __restrict__ ei, const float* __restrict__ dinv,
                              const float* __restrict__ B, float* __restrict__ A, int N, int E) {
  int r = blockIdx.y;
  int e = blockIdx.x * 2 + (threadIdx.x >> 7);
  int c = threadIdx.x & 127;
  if (e < E) {
    const int* base = ei + (size_t)edge_perm(r) * 2 * E;
    int src = base[e], dst = base[E + e];
    float nrm = dinv[(size_t)r * N + src] * dinv[(size_t)r * N + dst];
    atomicAdd(A + ((size_t)r * N + dst) * DD + c,
              B[((size_t)r * N + src) * DD + c] * nrm);
  }
}

__global__ void self_bias(float* __restrict__ A, const float* __restrict__ B,
                          const float* __restrict__ dinv, const float* __restrict__ bias, int N) {
  size_t i = (size_t)blockIdx.x * 256 + threadIdx.x;  // over 4*N*128
  size_t rn = i >> 7; int c = i & 127;
  if (rn < (size_t)4 * N) {
    float dv = dinv[rn];
    A[i] += B[i] * dv * dv + bias[c];
  }
}

// ---------------- batchnorm ----------------

__global__ void bn_stats(const float* __restrict__ A, float* __restrict__ sums, int N) {
  int r = blockIdx.y;
  int c = threadIdx.x & 127, g = threadIdx.x >> 7;
  float s = 0.f, s2 = 0.f;
  const float* base = A + (size_t)r * N * DD;
  for (int n = blockIdx.x * 2 + g; n < N; n += gridDim.x * 2) {
    float v = base[(size_t)n * DD + c];
    s += v; s2 += v * v;
  }
  __shared__ float ls[2][128], ls2[2][128];
  ls[g][c] = s; ls2[g][c] = s2;
  __syncthreads();
  if (g == 0) {
    atomicAdd(sums + (r * DD + c) * 2,     s + ls[1][c]);
    atomicAdd(sums + (r * DD + c) * 2 + 1, s2 + ls2[1][c]);
  }
}

__global__ void bn_final(const float* __restrict__ sums, const float* __restrict__ gamma,
                         const float* __restrict__ beta, float* __restrict__ ss, int N) {
  int t = threadIdx.x;       // 512 = r*128+c
  int c = t & 127;
  float mu = sums[t * 2] / N;
  float var = sums[t * 2 + 1] / N - mu * mu;
  float sc = gamma[c] * rsqrtf(var + 1e-5f);
  ss[t * 2] = sc;
  ss[t * 2 + 1] = beta[c] - mu * sc;
}

__global__ void bn_update(float* __restrict__ embs, const float* __restrict__ A,
                          const float* __restrict__ ss, int N) {
  size_t i = (size_t)blockIdx.x * 256 + threadIdx.x;
  if (i < (size_t)4 * N * DD) {
    size_t rn = i >> 7;
    int r = (int)(rn / (size_t)N);
    int c = i & 127;
    float sc = ss[(r * DD + c) * 2], sh = ss[(r * DD + c) * 2 + 1];
    float x = A[i] * sc + sh;
    embs[i] += x > 0.f ? x : 0.01f * x;
  }
}

__global__ void rels_update(const float* __restrict__ rin, const float* __restrict__ Wrt,
                            const float* __restrict__ brt, float* __restrict__ rout) {
  int t = threadIdx.x;  // 512 = r*128 + j
  int r = t >> 7, j = t & 127;
  float s = brt[j];
  const float* wr = Wrt + j * DD;
  const float* xr = rin + r * DD;
  for (int c = 0; c < DD; ++c) s += xr[c] * wr[c];
  rout[t] = s;
}

// ---------------- attention ----------------

__global__ void attn_scores(const float* __restrict__ Q, const float* __restrict__ K,
                            float* __restrict__ P, int N) {
  int sb = threadIdx.x >> 6;                // 4 nodes / block
  int node = blockIdx.x * 4 + sb;
  int lane = threadIdx.x & 63;
  __shared__ float qs[4][4][132], ks[4][4][132];
  if (node < N) {
#pragma unroll
    for (int p2 = 0; p2 < 2; ++p2) {
      int fidx = p2 * 64 + lane;            // float4 id 0..127
      int l = fidx >> 5; int c4 = (fidx & 31) * 4;
      *(float4*)(&qs[sb][l][c4]) = *(const float4*)(Q + ((size_t)l * N + node) * DD + c4);
      *(float4*)(&ks[sb][l][c4]) = *(const float4*)(K + ((size_t)l * N + node) * DD + c4);
    }
  }
  __syncthreads();
  if (node < N) {
    int h = lane >> 4, l = (lane >> 2) & 3, m = lane & 3;
    const float* qp = &qs[sb][l][h * 32];
    const float* kp = &ks[sb][m][h * 32];
    float s = 0.f;
#pragma unroll
    for (int k2 = 0; k2 < 32; ++k2) s += qp[k2] * kp[k2];
    s *= 0.17677669529663687f;              // 1/sqrt(32)
    float mx = s;
    mx = fmaxf(mx, __shfl_xor(mx, 1));
    mx = fmaxf(mx, __shfl_xor(mx, 2));
    float e = expf(s - mx);
    float sum = e;
    sum += __shfl_xor(sum, 1);
    sum += __shfl_xor(sum, 2);
    P[(size_t)node * 64 + lane] = e / sum;  // [node][h][l][m]
  }
}

__global__ void attn_apply(const float* __restrict__ P, const float* __restrict__ V,
                           float* __restrict__ O, int N) {
  int node = blockIdx.x * 2 + (threadIdx.x >> 7);
  int c = threadIdx.x & 127;
  if (node < N) {
    int h = c >> 5;
    float v0 = V[((size_t)0 * N + node) * DD + c];
    float v1 = V[((size_t)1 * N + node) * DD + c];
    float v2 = V[((size_t)2 * N + node) * DD + c];
    float v3 = V[((size_t)3 * N + node) * DD + c];
    const float* pp = P + (size_t)node * 64 + h * 16;
#pragma unroll
    for (int l = 0; l < 4; ++l) {
      float o = pp[l * 4 + 0] * v0 + pp[l * 4 + 1] * v1 + pp[l * 4 + 2] * v2 + pp[l * 4 + 3] * v3;
      O[((size_t)l * N + node) * DD + c] = o;
    }
  }
}

// f[l] = a[l]*proj[l] + (1-a[l])*stk[l],  stk[l] = A[p[l]], p = {3,0,2,1}
__global__ void blend(float* __restrict__ f, const float* __restrict__ proj,
                      const float* __restrict__ stkbase, const float* __restrict__ alphas, int N) {
  size_t NK = (size_t)N * DD;
  size_t i = (size_t)blockIdx.x * 256 + threadIdx.x;
  if (i < 4 * NK) {
    int l = (int)(i / NK);
    int pl = (l == 0) ? 3 : (l == 1) ? 0 : (l == 2) ? 2 : 1;
    float a = alphas[l];
    size_t off = i - (size_t)l * NK;
    f[i] = a * proj[i] + (1.f - a) * stkbase[(size_t)pl * NK + off];
  }
}

__global__ void score_reduce(const float* __restrict__ g, const float* __restrict__ q,
                             float* __restrict__ S, int N) {
  int l = blockIdx.y;
  int c = threadIdx.x & 127, gr = threadIdx.x >> 7;
  float qc = q[c];
  const float* base = g + (size_t)l * N * DD;
  float s = 0.f;
  for (int n = blockIdx.x * 2 + gr; n < N; n += gridDim.x * 2) {
    float v = base[(size_t)n * DD + c];
    v = v > 0.f ? v : 0.01f * v;
    s += v * qc;
  }
  __shared__ float red[256];
  red[threadIdx.x] = s; __syncthreads();
  for (int st = 128; st > 0; st >>= 1) {
    if (threadIdx.x < st) red[threadIdx.x] += red[threadIdx.x + st];
    __syncthreads();
  }
  if (threadIdx.x == 0) atomicAdd(S + l, red[0]);
}

// w = softmax([S(f0),S(f1),S(f3),S(f2)]);  coef[l] multiplies f[l]:
// coef = [w0, w1, w3, w2]
__global__ void wcoef(const float* __restrict__ S, float* __restrict__ coef, int N) {
  if (threadIdx.x == 0) {
    float v0 = S[0] / N, v1 = S[1] / N, v2 = S[3] / N, v3 = S[2] / N;
    float mx = fmaxf(fmaxf(v0, v1), fmaxf(v2, v3));
    float e0 = expf(v0 - mx), e1 = expf(v1 - mx), e2 = expf(v2 - mx), e3 = expf(v3 - mx);
    float inv = 1.f / (e0 + e1 + e2 + e3);
    coef[0] = e0 * inv; coef[1] = e1 * inv; coef[2] = e3 * inv; coef[3] = e2 * inv;
  }
}

// region = sum coef[l]*f[l]; outputs: region, region*rels3[{3,0,1,2}]
__global__ void final_out(const float* __restrict__ f, const float* __restrict__ coef,
                          const float* __restrict__ rels3, float* __restrict__ out, int N) {
  size_t NK = (size_t)N * DD;
  size_t i = (size_t)blockIdx.x * 256 + threadIdx.x;
  if (i < NK) {
    int c = i & 127;
    float region = coef[0] * f[i] + coef[1] * f[NK + i] + coef[2] * f[2 * NK + i] + coef[3] * f[3 * NK + i];
    out[i] = region;
    out[NK + i]     = region * rels3[3 * DD + c];
    out[2 * NK + i] = region * rels3[0 * DD + c];
    out[3 * NK + i] = region * rels3[1 * DD + c];
    out[4 * NK + i] = region * rels3[2 * DD + c];
  }
}

// ---------------- host ----------------

extern "C" void kernel_launch(void* const* d_in, const int* in_sizes, int n_in,
                              void* d_out, int out_size, void* d_ws, size_t ws_size,
                              hipStream_t stream) {
  const float* features  = (const float*)d_in[0];
  const float* rel_emb   = (const float*)d_in[1];
  const int*   edge_idx  = (const int*)d_in[2];
  const float* W_gcn     = (const float*)d_in[3];
  const float* b_gcn     = (const float*)d_in[4];
  const float* bn_gamma  = (const float*)d_in[5];
  const float* bn_beta   = (const float*)d_in[6];
  const float* W_rt      = (const float*)d_in[7];
  const float* b_rt      = (const float*)d_in[8];
  const float* attn_w_in = (const float*)d_in[9];
  const float* attn_b_in = (const float*)d_in[10];
  const float* attn_wout = (const float*)d_in[11];
  const float* attn_bout = (const float*)d_in[12];
  const float* alphas    = (const float*)d_in[13];
  const float* fusion_q  = (const float*)d_in[14];
  const float* fusion_w  = (const float*)d_in[15];
  const float* fusion_b  = (const float*)d_in[16];

  int N = in_sizes[0] / DD;                  // 50000
  int E = in_sizes[2] / (2 * NREL);          // 400000
  size_t NK = (size_t)N * DD;

  float* ws    = (float*)d_ws;
  float* A     = ws;                         // 4*NK
  float* B     = ws + 4 * NK;                // 4*NK
  float* dinv  = ws + 8 * NK;                // 4*N
  float* P     = dinv + 4 * (size_t)N;       // N*64
  float* Wsc   = P + (size_t)N * 64;         // 4*128*128
  float* wt    = Wsc + 4 * DD * DD;          // 5*128*128
  float* rels  = wt + 5 * DD * DD;           // 4 stages * 512
  float* bnsum = rels + 4 * 512;             // 1024
  float* bnss  = bnsum + 1024;               // 1024
  float* S     = bnss + 1024;                // 4
  float* C     = (float*)d_out;              // 5*NK; slices 0..3 = embs scratch
  float* coef  = S + 4;                      // 4

  size_t needed = (size_t)(coef + 4 - ws) * sizeof(float);
  if (ws_size < needed) {
    fprintf(stderr, "kernel_launch: ws too small (%zu < %zu)\n", ws_size, needed);
    return;
  }

  int nkb = (int)((4 * NK + 255) / 256);
  int gemmGrid = (N + 63) / 64;

  // degrees -> dinv (edges fixed across layers)
  hipMemsetAsync(dinv, 0, (size_t)4 * N * sizeof(float), stream);
  count_deg<<<dim3((E + 255) / 256, 4), 256, 0, stream>>>(edge_idx, dinv, N, E);
  finalize_dinv<<<(4 * N + 255) / 256, 256, 0, stream>>>(dinv, 4 * N);

  init_embs<<<(int)((NK + 255) / 256), 256, 0, stream>>>(features, C, NK);
  rels_init<<<1, 512, 0, stream>>>(rel_emb, rels);
  transpose_w<<<(5 * 16384) / 256, 256, 0, stream>>>(attn_w_in, attn_wout, fusion_w, wt);

  Ptr4 xs, wz; Out4 ys;
  for (int i = 0; i < 3; ++i) {
    scale_w<<<256, 256, 0, stream>>>(rels + i * 512, W_gcn + (size_t)i * DD * DD, Wsc);
    for (int r = 0; r < 4; ++r) {
      xs.p[r] = C + r * NK; wz.p[r] = Wsc + r * DD * DD; ys.p[r] = B + r * NK;
    }
    gemm4<<<dim3(gemmGrid, 4), 256, 0, stream>>>(xs, wz, ys, nullptr, N);
    hipMemsetAsync(A, 0, 4 * NK * sizeof(float), stream);
    scatter_edges<<<dim3((E + 1) / 2, 4), 256, 0, stream>>>(edge_idx, dinv, B, A, N, E);
    self_bias<<<nkb, 256, 0, stream>>>(A, B, dinv, b_gcn + i * DD, N);
    if (i < 2) {
      hipMemsetAsync(bnsum, 0, 1024 * sizeof(float), stream);
      bn_stats<<<dim3(128, 4), 256, 0, stream>>>(A, bnsum, N);
      bn_final<<<1, 512, 0, stream>>>(bnsum, bn_gamma + i * DD, bn_beta + i * DD, bnss, N);
      bn_update<<<nkb, 256, 0, stream>>>(C, A, bnss, N);
    }
    rels_update<<<1, 512, 0, stream>>>(rels + i * 512, W_rt + (size_t)i * DD * DD,
                                       b_rt + i * DD, rels + (i + 1) * 512);
  }
  // A now holds final GCN outputs (the stack source); C (embs) is dead.

  const int pstk[4] = {3, 0, 2, 1};
  Ptr4 stk, w4, fromB, fromC; Out4 toB, toC;
  for (int l = 0; l < 4; ++l) {
    stk.p[l] = A + (size_t)pstk[l] * NK;
    toB.p[l] = B + (size_t)l * NK; toC.p[l] = C + (size_t)l * NK;
    fromB.p[l] = B + (size_t)l * NK; fromC.p[l] = C + (size_t)l * NK;
  }

  for (int l = 0; l < 4; ++l) w4.p[l] = wt;                       // Wq^T
  gemm4<<<dim3(gemmGrid, 4), 256, 0, stream>>>(stk, w4, toC, attn_b_in, N);        // Q -> C
  for (int l = 0; l < 4; ++l) w4.p[l] = wt + 16384;               // Wk^T
  gemm4<<<dim3(gemmGrid, 4), 256, 0, stream>>>(stk, w4, toB, attn_b_in + DD, N);   // K -> B
  attn_scores<<<(N + 3) / 4, 256, 0, stream>>>(C, B, P, N);
  for (int l = 0; l < 4; ++l) w4.p[l] = wt + 2 * 16384;           // Wv^T
  gemm4<<<dim3(gemmGrid, 4), 256, 0, stream>>>(stk, w4, toB, attn_b_in + 2 * DD, N); // V -> B
  attn_apply<<<(N + 1) / 2, 256, 0, stream>>>(P, B, C, N);        // o -> C
  for (int l = 0; l < 4; ++l) w4.p[l] = wt + 3 * 16384;           // Wout^T
  gemm4<<<dim3(gemmGrid, 4), 256, 0, stream>>>(fromC, w4, toB, attn_bout, N);      // proj -> B
  blend<<<nkb, 256, 0, stream>>>(C, B, A, alphas, N);             // f -> C
  for (int l = 0; l < 4; ++l) w4.p[l] = wt + 4 * 16384;           // Wfus^T
  gemm4<<<dim3(gemmGrid, 4), 256, 0, stream>>>(fromC, w4, toB, fusion_b, N);       // g -> B
  hipMemsetAsync(S, 0, 4 * sizeof(float), stream);
  score_reduce<<<dim3(128, 4), 256, 0, stream>>>(B, fusion_q, S, N);
  wcoef<<<1, 64, 0, stream>>>(S, coef, N);
  final_out<<<(int)((NK + 255) / 256), 256, 0, stream>>>(C, coef, rels + 3 * 512, (float*)d_out, N);
}

// Round 2
// 2207.673 us; speedup vs baseline: 1.7816x; 1.7816x over previous
//
#include <hip/hip_runtime.h>
#include <cstdio>

#define DD 128
#define NREL 4

struct Ptr4 { const float* p[4]; };
struct Out4 { float* p[4]; };

// processing-order relation r uses edge_index/rel_emb row (r+3)&3  (perm = [3,0,1,2])
__device__ __forceinline__ int edge_perm(int r) { return (r + 3) & 3; }

__device__ __forceinline__ float bf_lo(unsigned u) { return __uint_as_float(u << 16); }
__device__ __forceinline__ float bf_hi(unsigned u) { return __uint_as_float(u & 0xffff0000u); }
__device__ __forceinline__ unsigned short f2bf(float f) {
  unsigned x = __float_as_uint(f);
  unsigned r = (x + 0x7fffu + ((x >> 16) & 1u)) >> 16;
  return (unsigned short)r;
}

// ---------------- init ----------------

__global__ void rels_init(const float* __restrict__ rel_emb, float* __restrict__ rels) {
  int t = threadIdx.x;              // 512 = r*128 + c
  int r = t >> 7, c = t & 127;
  rels[t] = rel_emb[edge_perm(r) * DD + c];
}

// wt[z][c][j] = W_z[j][c]; z: 0=q 1=k 2=v 3=out 4=fusion
__global__ void transpose_w(const float* __restrict__ w_in, const float* __restrict__ w_out,
                            const float* __restrict__ w_fus, float* __restrict__ wt) {
  int i = blockIdx.x * 256 + threadIdx.x;   // 5*16384
  int z = i >> 14, rem = i & 16383;
  int c = rem >> 7, j = rem & 127;
  float v;
  if (z < 3) v = w_in[(z * DD + j) * DD + c];
  else if (z == 3) v = w_out[j * DD + c];
  else v = w_fus[j * DD + c];
  wt[i] = v;
}

__global__ void count_deg(const int* __restrict__ ei, int* __restrict__ deg, int N, int E) {
  int r = blockIdx.y;
  int e = blockIdx.x * 256 + threadIdx.x;
  if (e < E) {
    int dst = ei[(size_t)edge_perm(r) * 2 * E + E + e];
    atomicAdd(deg + (size_t)r * N + dst, 1);
  }
}

__global__ void finalize_dinv(const int* __restrict__ deg, float* __restrict__ dinv, int total) {
  int i = blockIdx.x * 256 + threadIdx.x;
  if (i < total) dinv[i] = rsqrtf((float)deg[i] + 1.0f);
}

// ---------------- CSR build: block scan ----------------

__global__ void scan_block(const int* __restrict__ deg, int* __restrict__ excl,
                           int* __restrict__ bsums, int n) {
  __shared__ int sh[256];
  int i = blockIdx.x * 256 + threadIdx.x;
  int v = (i < n) ? deg[i] : 0;
  sh[threadIdx.x] = v;
  __syncthreads();
  for (int st = 1; st < 256; st <<= 1) {
    int t = (threadIdx.x >= st) ? sh[threadIdx.x - st] : 0;
    __syncthreads();
    sh[threadIdx.x] += t;
    __syncthreads();
  }
  if (i < n) excl[i] = sh[threadIdx.x] - v;
  if (threadIdx.x == 255) bsums[blockIdx.x] = sh[255];
}

__global__ void scan_sums(int* __restrict__ bsums, int nb) {
  __shared__ int sh[1024];
  int v = (threadIdx.x < nb) ? bsums[threadIdx.x] : 0;
  sh[threadIdx.x] = v;
  __syncthreads();
  for (int st = 1; st < 1024; st <<= 1) {
    int t = (threadIdx.x >= st) ? sh[threadIdx.x - st] : 0;
    __syncthreads();
    sh[threadIdx.x] += t;
    __syncthreads();
  }
  if (threadIdx.x < nb) bsums[threadIdx.x] = sh[threadIdx.x] - v;  // exclusive
}

__global__ void scan_add(int* __restrict__ excl, int* __restrict__ cursor,
                         const int* __restrict__ bsums, int n) {
  int i = blockIdx.x * 256 + threadIdx.x;
  if (i < n) {
    int o = excl[i] + bsums[blockIdx.x];
    excl[i] = o;
    cursor[i] = o;
  }
}

__global__ void fill_edges(const int* __restrict__ ei, int* __restrict__ cursor,
                           int* __restrict__ srcbuf, int N, int E) {
  int r = blockIdx.y;
  int e = blockIdx.x * 256 + threadIdx.x;
  if (e < E) {
    const int* base = ei + (size_t)edge_perm(r) * 2 * E;
    int src = base[e], dst = base[E + e];
    int pos = atomicAdd(&cursor[r * N + dst], 1);
    srcbuf[pos] = r * N + src;   // global row index into Bs
  }
}

// ---------------- GEMM: Y[M,128] = X[M,128] @ W[128,128] (+bias) , z-batched x4 ----------------
__global__ __launch_bounds__(256) void gemm4(Ptr4 xs, Ptr4 wz, Out4 ys,
                                             const float* __restrict__ bias, int M) {
  int z = blockIdx.y;
  const float* __restrict__ X = xs.p[z];
  const float* __restrict__ W = wz.p[z];
  float* __restrict__ Y = ys.p[z];
  int row0 = blockIdx.x * 64;
  __shared__ float Xs[64][132];             // +4 pad: conflict-free column reads
  int tid = threadIdx.x;
#pragma unroll
  for (int it = 0; it < 8; ++it) {
    int idx = it * 256 + tid;               // float4 id 0..2047
    int rr = idx >> 5, cc = (idx & 31) * 4;
    float4 v = make_float4(0.f, 0.f, 0.f, 0.f);
    if (row0 + rr < M) v = *(const float4*)(X + (size_t)(row0 + rr) * DD + cc);
    *(float4*)(&Xs[rr][cc]) = v;
  }
  __syncthreads();
  int tx = tid & 15, ty = tid >> 4;         // cols tx*8..+7, rows ty*4..+3
  float acc[4][8];
#pragma unroll
  for (int i = 0; i < 4; ++i)
#pragma unroll
    for (int j = 0; j < 8; ++j) acc[i][j] = 0.f;
  const float* Wp = W + tx * 8;
#pragma unroll 4
  for (int kk = 0; kk < 128; ++kk) {
    float4 w0 = *(const float4*)(Wp + kk * DD);
    float4 w1 = *(const float4*)(Wp + kk * DD + 4);
#pragma unroll
    for (int i = 0; i < 4; ++i) {
      float xv = Xs[ty * 4 + i][kk];
      acc[i][0] += xv * w0.x; acc[i][1] += xv * w0.y;
      acc[i][2] += xv * w0.z; acc[i][3] += xv * w0.w;
      acc[i][4] += xv * w1.x; acc[i][5] += xv * w1.y;
      acc[i][6] += xv * w1.z; acc[i][7] += xv * w1.w;
    }
  }
  float b0[8];
#pragma unroll
  for (int j = 0; j < 8; ++j) b0[j] = bias ? bias[tx * 8 + j] : 0.f;
#pragma unroll
  for (int i = 0; i < 4; ++i) {
    int row = row0 + ty * 4 + i;
    if (row < M) {
      float4 o0 = make_float4(acc[i][0] + b0[0], acc[i][1] + b0[1], acc[i][2] + b0[2], acc[i][3] + b0[3]);
      float4 o1 = make_float4(acc[i][4] + b0[4], acc[i][5] + b0[5], acc[i][6] + b0[6], acc[i][7] + b0[7]);
      *(float4*)(Y + (size_t)row * DD + tx * 8) = o0;
      *(float4*)(Y + (size_t)row * DD + tx * 8 + 4) = o1;
    }
  }
}

// GCN message GEMM: Bs[z*N+row][c] = bf16( (X@W)[row][c] * dinv[z*N+row] )
__global__ __launch_bounds__(256) void gemm4_gcn(Ptr4 xs, Ptr4 wz, unsigned short* __restrict__ Bs,
                                                 const float* __restrict__ dinv, int M) {
  int z = blockIdx.y;
  const float* __restrict__ X = xs.p[z];
  const float* __restrict__ W = wz.p[z];
  int row0 = blockIdx.x * 64;
  __shared__ float Xs[64][132];
  int tid = threadIdx.x;
#pragma unroll
  for (int it = 0; it < 8; ++it) {
    int idx = it * 256 + tid;
    int rr = idx >> 5, cc = (idx & 31) * 4;
    float4 v = make_float4(0.f, 0.f, 0.f, 0.f);
    if (row0 + rr < M) v = *(const float4*)(X + (size_t)(row0 + rr) * DD + cc);
    *(float4*)(&Xs[rr][cc]) = v;
  }
  __syncthreads();
  int tx = tid & 15, ty = tid >> 4;
  float acc[4][8];
#pragma unroll
  for (int i = 0; i < 4; ++i)
#pragma unroll
    for (int j = 0; j < 8; ++j) acc[i][j] = 0.f;
  const float* Wp = W + tx * 8;
#pragma unroll 4
  for (int kk = 0; kk < 128; ++kk) {
    float4 w0 = *(const float4*)(Wp + kk * DD);
    float4 w1 = *(const float4*)(Wp + kk * DD + 4);
#pragma unroll
    for (int i = 0; i < 4; ++i) {
      float xv = Xs[ty * 4 + i][kk];
      acc[i][0] += xv * w0.x; acc[i][1] += xv * w0.y;
      acc[i][2] += xv * w0.z; acc[i][3] += xv * w0.w;
      acc[i][4] += xv * w1.x; acc[i][5] += xv * w1.y;
      acc[i][6] += xv * w1.z; acc[i][7] += xv * w1.w;
    }
  }
#pragma unroll
  for (int i = 0; i < 4; ++i) {
    int row = row0 + ty * 4 + i;
    if (row < M) {
      size_t rg = (size_t)z * M + row;
      float dv = dinv[rg];
      unsigned pk[4];
#pragma unroll
      for (int jj = 0; jj < 4; ++jj) {
        pk[jj] = (unsigned)f2bf(acc[i][2 * jj] * dv) |
                 ((unsigned)f2bf(acc[i][2 * jj + 1] * dv) << 16);
      }
      *(uint4*)(Bs + rg * DD + tx * 8) = make_uint4(pk[0], pk[1], pk[2], pk[3]);
    }
  }
}

// ---------------- GCN aggregation: CSR gather (one wave per (r,node)) ----------------
// A[rn][c] = dinv[rn] * ( sum_{src in csr[rn]} Bs[src][c] + Bs[rn][c] ) + bias[c]
__global__ __launch_bounds__(256) void gather_agg(const int* __restrict__ srcbuf,
                                                  const int* __restrict__ offsets,
                                                  const int* __restrict__ deg,
                                                  const float* __restrict__ dinv,
                                                  const unsigned* __restrict__ Bs,
                                                  const float* __restrict__ bias,
                                                  float* __restrict__ A, int N) {
  int rn = blockIdx.x * 4 + (threadIdx.x >> 6);
  if (rn >= 4 * N) return;
  int lane = threadIdx.x & 63;
  int st = offsets[rn];
  int cnt = deg[rn];
  unsigned u = Bs[(size_t)rn * 64 + lane];        // self message
  float a0 = bf_lo(u), a1 = bf_hi(u);
  for (int e = 0; e < cnt; ++e) {
    int row = srcbuf[st + e];
    unsigned v = Bs[(size_t)row * 64 + lane];
    a0 += bf_lo(v); a1 += bf_hi(v);
  }
  float dv = dinv[rn];
  int c = lane * 2;
  float2 o = make_float2(a0 * dv + bias[c], a1 * dv + bias[c + 1]);
  *(float2*)(A + (size_t)rn * DD + c) = o;
}

// ---------------- batchnorm ----------------

__global__ void bn_stats(const float* __restrict__ A, float* __restrict__ sums, int N) {
  int r = blockIdx.y;
  int c = threadIdx.x & 127, g = threadIdx.x >> 7;
  float s = 0.f, s2 = 0.f;
  const float* base = A + (size_t)r * N * DD;
  for (int n = blockIdx.x * 2 + g; n < N; n += gridDim.x * 2) {
    float v = base[(size_t)n * DD + c];
    s += v; s2 += v * v;
  }
  __shared__ float ls[2][128], ls2[2][128];
  ls[g][c] = s; ls2[g][c] = s2;
  __syncthreads();
  if (g == 0) {
    atomicAdd(sums + (r * DD + c) * 2,     s + ls[1][c]);
    atomicAdd(sums + (r * DD + c) * 2 + 1, s2 + ls2[1][c]);
  }
}

__global__ void bn_final(const float* __restrict__ sums, const float* __restrict__ gamma,
                         const float* __restrict__ beta, float* __restrict__ ss, int N) {
  int t = threadIdx.x;       // 512 = r*128+c
  int c = t & 127;
  float mu = sums[t * 2] / N;
  float var = sums[t * 2 + 1] / N - mu * mu;
  float sc = gamma[c] * rsqrtf(var + 1e-5f);
  ss[t * 2] = sc;
  ss[t * 2 + 1] = beta[c] - mu * sc;
}

// base0 == null: embs += leaky(A*sc+sh)   (in-place residual)
// base0 != null: embs = base0[node-broadcast] + leaky(A*sc+sh)
__global__ void bn_update(float* __restrict__ embs, const float* __restrict__ A,
                          const float* __restrict__ ss, const float* __restrict__ base0, int N) {
  size_t i = (size_t)blockIdx.x * 256 + threadIdx.x;
  size_t NK = (size_t)N * DD;
  if (i < 4 * NK) {
    size_t rn = i >> 7;
    int r = (int)(rn / (size_t)N);
    int c = i & 127;
    float sc = ss[(r * DD + c) * 2], sh = ss[(r * DD + c) * 2 + 1];
    float x = A[i] * sc + sh;
    x = x > 0.f ? x : 0.01f * x;
    float b = base0 ? base0[i - (size_t)r * NK] : embs[i];
    embs[i] = b + x;
  }
}

__global__ void rels_update(const float* __restrict__ rin, const float* __restrict__ Wrt,
                            const float* __restrict__ brt, float* __restrict__ rout) {
  int t = threadIdx.x;  // 512 = r*128 + j
  int r = t >> 7, j = t & 127;
  float s = brt[j];
  const float* wr = Wrt + j * DD;
  const float* xr = rin + r * DD;
  for (int c = 0; c < DD; ++c) s += xr[c] * wr[c];
  rout[t] = s;
}

// ---------------- attention ----------------

__global__ void attn_scores(const float* __restrict__ Q, const float* __restrict__ K,
                            float* __restrict__ P, int N) {
  int sb = threadIdx.x >> 6;                // 4 nodes / block
  int node = blockIdx.x * 4 + sb;
  int lane = threadIdx.x & 63;
  __shared__ float qs[4][4][132], ks[4][4][132];
  if (node < N) {
#pragma unroll
    for (int p2 = 0; p2 < 2; ++p2) {
      int fidx = p2 * 64 + lane;            // float4 id 0..127
      int l = fidx >> 5; int c4 = (fidx & 31) * 4;
      *(float4*)(&qs[sb][l][c4]) = *(const float4*)(Q + ((size_t)l * N + node) * DD + c4);
      *(float4*)(&ks[sb][l][c4]) = *(const float4*)(K + ((size_t)l * N + node) * DD + c4);
    }
  }
  __syncthreads();
  if (node < N) {
    int h = lane >> 4, l = (lane >> 2) & 3, m = lane & 3;
    const float* qp = &qs[sb][l][h * 32];
    const float* kp = &ks[sb][m][h * 32];
    float s = 0.f;
#pragma unroll
    for (int k2 = 0; k2 < 32; ++k2) s += qp[k2] * kp[k2];
    s *= 0.17677669529663687f;              // 1/sqrt(32)
    float mx = s;
    mx = fmaxf(mx, __shfl_xor(mx, 1));
    mx = fmaxf(mx, __shfl_xor(mx, 2));
    float e = expf(s - mx);
    float sum = e;
    sum += __shfl_xor(sum, 1);
    sum += __shfl_xor(sum, 2);
    P[(size_t)node * 64 + lane] = e / sum;  // [node][h][l][m]
  }
}

__global__ void attn_apply(const float* __restrict__ P, const float* __restrict__ V,
                           float* __restrict__ O, int N) {
  int node = blockIdx.x * 2 + (threadIdx.x >> 7);
  int c = threadIdx.x & 127;
  if (node < N) {
    int h = c >> 5;
    float v0 = V[((size_t)0 * N + node) * DD + c];
    float v1 = V[((size_t)1 * N + node) * DD + c];
    float v2 = V[((size_t)2 * N + node) * DD + c];
    float v3 = V[((size_t)3 * N + node) * DD + c];
    const float* pp = P + (size_t)node * 64 + h * 16;
#pragma unroll
    for (int l = 0; l < 4; ++l) {
      float o = pp[l * 4 + 0] * v0 + pp[l * 4 + 1] * v1 + pp[l * 4 + 2] * v2 + pp[l * 4 + 3] * v3;
      O[((size_t)l * N + node) * DD + c] = o;
    }
  }
}

// f[l] = a[l]*proj[l] + (1-a[l])*stk[l],  stk[l] = A[p[l]], p = {3,0,2,1}
__global__ void blend(float* __restrict__ f, const float* __restrict__ proj,
                      const float* __restrict__ stkbase, const float* __restrict__ alphas, int N) {
  size_t NK = (size_t)N * DD;
  size_t i = (size_t)blockIdx.x * 256 + threadIdx.x;
  if (i < 4 * NK) {
    int l = (int)(i / NK);
    int pl = (l == 0) ? 3 : (l == 1) ? 0 : (l == 2) ? 2 : 1;
    float a = alphas[l];
    size_t off = i - (size_t)l * NK;
    f[i] = a * proj[i] + (1.f - a) * stkbase[(size_t)pl * NK + off];
  }
}

__global__ void score_reduce(const float* __restrict__ g, const float* __restrict__ q,
                             float* __restrict__ S, int N) {
  int l = blockIdx.y;
  int c = threadIdx.x & 127, gr = threadIdx.x >> 7;
  float qc = q[c];
  const float* base = g + (size_t)l * N * DD;
  float s = 0.f;
  for (int n = blockIdx.x * 2 + gr; n < N; n += gridDim.x * 2) {
    float v = base[(size_t)n * DD + c];
    v = v > 0.f ? v : 0.01f * v;
    s += v * qc;
  }
  __shared__ float red[256];
  red[threadIdx.x] = s; __syncthreads();
  for (int st = 128; st > 0; st >>= 1) {
    if (threadIdx.x < st) red[threadIdx.x] += red[threadIdx.x + st];
    __syncthreads();
  }
  if (threadIdx.x == 0) atomicAdd(S + l, red[0]);
}

// w = softmax([S(f0),S(f1),S(f3),S(f2)]);  coef[l] multiplies f[l]: coef = [w0,w1,w3,w2]
__global__ void wcoef(const float* __restrict__ S, float* __restrict__ coef, int N) {
  if (threadIdx.x == 0) {
    float v0 = S[0] / N, v1 = S[1] / N, v2 = S[3] / N, v3 = S[2] / N;
    float mx = fmaxf(fmaxf(v0, v1), fmaxf(v2, v3));
    float e0 = expf(v0 - mx), e1 = expf(v1 - mx), e2 = expf(v2 - mx), e3 = expf(v3 - mx);
    float inv = 1.f / (e0 + e1 + e2 + e3);
    coef[0] = e0 * inv; coef[1] = e1 * inv; coef[2] = e3 * inv; coef[3] = e2 * inv;
  }
}

// region = sum coef[l]*f[l]; outputs: region, region*rels3[{3,0,1,2}]
__global__ void final_out(const float* __restrict__ f, const float* __restrict__ coef,
                          const float* __restrict__ rels3, float* __restrict__ out, int N) {
  size_t NK = (size_t)N * DD;
  size_t i = (size_t)blockIdx.x * 256 + threadIdx.x;
  if (i < NK) {
    int c = i & 127;
    float region = coef[0] * f[i] + coef[1] * f[NK + i] + coef[2] * f[2 * NK + i] + coef[3] * f[3 * NK + i];
    out[i] = region;
    out[NK + i]     = region * rels3[3 * DD + c];
    out[2 * NK + i] = region * rels3[0 * DD + c];
    out[3 * NK + i] = region * rels3[1 * DD + c];
    out[4 * NK + i] = region * rels3[2 * DD + c];
  }
}

// ---------------- host ----------------

extern "C" void kernel_launch(void* const* d_in, const int* in_sizes, int n_in,
                              void* d_out, int out_size, void* d_ws, size_t ws_size,
                              hipStream_t stream) {
  const float* features  = (const float*)d_in[0];
  const float* rel_emb   = (const float*)d_in[1];
  const int*   edge_idx  = (const int*)d_in[2];
  const float* W_gcn     = (const float*)d_in[3];
  const float* b_gcn     = (const float*)d_in[4];
  const float* bn_gamma  = (const float*)d_in[5];
  const float* bn_beta   = (const float*)d_in[6];
  const float* W_rt      = (const float*)d_in[7];
  const float* b_rt      = (const float*)d_in[8];
  const float* attn_w_in = (const float*)d_in[9];
  const float* attn_b_in = (const float*)d_in[10];
  const float* attn_wout = (const float*)d_in[11];
  const float* attn_bout = (const float*)d_in[12];
  const float* alphas    = (const float*)d_in[13];
  const float* fusion_q  = (const float*)d_in[14];
  const float* fusion_w  = (const float*)d_in[15];
  const float* fusion_b  = (const float*)d_in[16];

  int N = in_sizes[0] / DD;                  // 50000
  int E = in_sizes[2] / (2 * NREL);          // 400000
  size_t NK = (size_t)N * DD;
  int N4 = 4 * N;

  float* ws    = (float*)d_ws;
  float* A     = ws;                         // 4*NK
  float* B     = ws + 4 * NK;                // 4*NK (fp32, attention phase)
  float* dinv  = ws + 8 * NK;                // 4*N
  float* P     = dinv + N4;                  // N*64
  float* Wsc   = P + (size_t)N * 64;         // 4*128*128
  float* wt    = Wsc + 4 * DD * DD;          // 5*128*128
  float* rels  = wt + 5 * DD * DD;           // 4 stages * 512
  float* bnsum = rels + 4 * 512;             // 1024
  float* bnss  = bnsum + 1024;               // 1024
  float* S     = bnss + 1024;                // 4
  float* coef  = S + 4;                      // 4
  int*   deg_i = (int*)(coef + 4);           // 4*N
  int*   offs  = deg_i + N4;                 // 4*N
  int*   cur   = offs + N4;                  // 4*N
  int*   bsums = cur + N4;                   // 1024
  int*   srcb  = bsums + 1024;               // 4*E
  float* C     = (float*)d_out;              // 5*NK; slices 0..3 = embs scratch

  unsigned short* Bs = (unsigned short*)B;   // bf16 messages alias B (GCN phase only)

  size_t needed = (size_t)((float*)(srcb + 4 * E) - ws) * sizeof(float);
  if (ws_size < needed) {
    fprintf(stderr, "kernel_launch: ws too small (%zu < %zu)\n", ws_size, needed);
    return;
  }

  int nkb = (int)((4 * NK + 255) / 256);
  int gemmGrid = (N + 63) / 64;
  int scanBlocks = (N4 + 255) / 256;
  int egrid = (E + 255) / 256;

  // ---- CSR build (edges fixed across layers) ----
  hipMemsetAsync(deg_i, 0, (size_t)N4 * sizeof(int), stream);
  count_deg<<<dim3(egrid, 4), 256, 0, stream>>>(edge_idx, deg_i, N, E);
  finalize_dinv<<<scanBlocks, 256, 0, stream>>>(deg_i, dinv, N4);
  scan_block<<<scanBlocks, 256, 0, stream>>>(deg_i, offs, bsums, N4);
  scan_sums<<<1, 1024, 0, stream>>>(bsums, scanBlocks);
  scan_add<<<scanBlocks, 256, 0, stream>>>(offs, cur, bsums, N4);
  fill_edges<<<dim3(egrid, 4), 256, 0, stream>>>(edge_idx, cur, srcb, N, E);

  rels_init<<<1, 512, 0, stream>>>(rel_emb, rels);
  transpose_w<<<(5 * 16384) / 256, 256, 0, stream>>>(attn_w_in, attn_wout, fusion_w, wt);

  // ---- GCN layers ----
  Ptr4 xs, wz;
  for (int i = 0; i < 3; ++i) {
    // fold rels column-scale into W: Ws[r][c][j] = rels[r][c] * Wg[c][j]
    {
      struct ScaleW {
        static __global__ void k(const float* rels_i, const float* Wg, float* Ws) {
          int i = blockIdx.x * 256 + threadIdx.x;
          int r = i >> 14, rem = i & 16383, c = rem >> 7;
          Ws[i] = rels_i[r * DD + c] * Wg[rem];
        }
      };
      // (defined inline to keep diff local; see scale_w below)
    }
    // launch scale_w
    extern __global__ void scale_w(const float*, const float*, float*);
    scale_w<<<256, 256, 0, stream>>>(rels + i * 512, W_gcn + (size_t)i * DD * DD, Wsc);
    for (int r = 0; r < 4; ++r) {
      xs.p[r] = (i == 0) ? features : (C + (size_t)r * NK);
      wz.p[r] = Wsc + (size_t)r * DD * DD;
    }
    gemm4_gcn<<<dim3(gemmGrid, 4), 256, 0, stream>>>(xs, wz, Bs, dinv, N);
    gather_agg<<<(N4 + 3) / 4, 256, 0, stream>>>(srcb, offs, deg_i, dinv,
                                                 (const unsigned*)Bs, b_gcn + i * DD, A, N);
    if (i < 2) {
      hipMemsetAsync(bnsum, 0, 1024 * sizeof(float), stream);
      bn_stats<<<dim3(128, 4), 256, 0, stream>>>(A, bnsum, N);
      bn_final<<<1, 512, 0, stream>>>(bnsum, bn_gamma + i * DD, bn_beta + i * DD, bnss, N);
      bn_update<<<nkb, 256, 0, stream>>>(C, A, bnss, (i == 0) ? features : nullptr, N);
    }
    rels_update<<<1, 512, 0, stream>>>(rels + i * 512, W_rt + (size_t)i * DD * DD,
                                       b_rt + i * DD, rels + (i + 1) * 512);
  }
  // A now holds final GCN outputs (the stack source); C slices 0..3 hold embs (dead).

  const int pstk[4] = {3, 0, 2, 1};
  Ptr4 stk, w4, fromC;
  Out4 toB, toC;
  for (int l = 0; l < 4; ++l) {
    stk.p[l] = A + (size_t)pstk[l] * NK;
    toB.p[l] = B + (size_t)l * NK; toC.p[l] = C + (size_t)l * NK;
    fromC.p[l] = C + (size_t)l * NK;
  }

  for (int l = 0; l < 4; ++l) w4.p[l] = wt;                       // Wq^T
  gemm4<<<dim3(gemmGrid, 4), 256, 0, stream>>>(stk, w4, toC, attn_b_in, N);          // Q -> C
  for (int l = 0; l < 4; ++l) w4.p[l] = wt + 16384;               // Wk^T
  gemm4<<<dim3(gemmGrid, 4), 256, 0, stream>>>(stk, w4, toB, attn_b_in + DD, N);     // K -> B
  attn_scores<<<(N + 3) / 4, 256, 0, stream>>>(C, B, P, N);
  for (int l = 0; l < 4; ++l) w4.p[l] = wt + 2 * 16384;           // Wv^T
  gemm4<<<dim3(gemmGrid, 4), 256, 0, stream>>>(stk, w4, toB, attn_b_in + 2 * DD, N); // V -> B
  attn_apply<<<(N + 1) / 2, 256, 0, stream>>>(P, B, C, N);        // o -> C
  for (int l = 0; l < 4; ++l) w4.p[l] = wt + 3 * 16384;           // Wout^T
  gemm4<<<dim3(gemmGrid, 4), 256, 0, stream>>>(fromC, w4, toB, attn_bout, N);        // proj -> B
  blend<<<nkb, 256, 0, stream>>>(C, B, A, alphas, N);             // f -> C
  for (int l = 0; l < 4; ++l) w4.p[l] = wt + 4 * 16384;           // Wfus^T
  gemm4<<<dim3(gemmGrid, 4), 256, 0, stream>>>(fromC, w4, toB, fusion_b, N);         // g -> B
  hipMemsetAsync(S, 0, 4 * sizeof(float), stream);
  score_reduce<<<dim3(128, 4), 256, 0, stream>>>(B, fusion_q, S, N);
  wcoef<<<1, 64, 0, stream>>>(S, coef, N);
  final_out<<<(int)((NK + 255) / 256), 256, 0, stream>>>(C, coef, rels + 3 * 512, (float*)d_out, N);
}

// Ws[r][c][j] = rels[r][c] * Wg[c][j]   (fold column scale into weight)
__global__ void scale_w(const float* __restrict__ rels_i, const float* __restrict__ Wg,
                        float* __restrict__ Ws) {
  int i = blockIdx.x * 256 + threadIdx.x;   // 4*16384
  int r = i >> 14, rem = i & 16383, c = rem >> 7;
  Ws[i] = rels_i[r * DD + c] * Wg[rem];
}

// Round 4
// 1340.001 us; speedup vs baseline: 2.9352x; 1.6475x over previous
//
#include <hip/hip_runtime.h>
#include <cstdio>

#define DD 128
#define NREL 4

using short8 = __attribute__((ext_vector_type(8))) short;
using f32x4  = __attribute__((ext_vector_type(4))) float;

struct PtrB4 { const unsigned short* p[4]; };
struct OutB4 { unsigned short* p[4]; };

// processing-order relation r uses edge_index/rel_emb row (r+3)&3  (perm = [3,0,1,2])
__device__ __forceinline__ int edge_perm(int r) { return (r + 3) & 3; }

__device__ __forceinline__ float bf_lo(unsigned u) { return __uint_as_float(u << 16); }
__device__ __forceinline__ float bf_hi(unsigned u) { return __uint_as_float(u & 0xffff0000u); }
__device__ __forceinline__ unsigned short f2bf(float f) {
  unsigned x = __float_as_uint(f);
  unsigned r = (x + 0x7fffu + ((x >> 16) & 1u)) >> 16;
  return (unsigned short)r;
}
__device__ __forceinline__ unsigned pack2(float a, float b) {
  return (unsigned)f2bf(a) | ((unsigned)f2bf(b) << 16);
}

// ---------------- init / weight prep ----------------

__global__ void rels_init(const float* __restrict__ rel_emb, float* __restrict__ rels) {
  int t = threadIdx.x;              // 512 = r*128 + c
  int r = t >> 7, c = t & 127;
  rels[t] = rel_emb[edge_perm(r) * DD + c];
}

__global__ void rels_update(const float* __restrict__ rin, const float* __restrict__ Wrt,
                            const float* __restrict__ brt, float* __restrict__ rout) {
  int t = threadIdx.x;  // 512 = r*128 + j
  int r = t >> 7, j = t & 127;
  float s = brt[j];
  const float* wr = Wrt + j * DD;
  const float* xr = rin + r * DD;
  for (int c = 0; c < DD; ++c) s += xr[c] * wr[c];
  rout[t] = s;
}

// Wsb[r][j][c] = bf16(rels[r][c] * Wg[c][j])  -- MFMA-B layout [n=j][k=c]
__global__ void scale_w_bf(const float* __restrict__ rels_i, const float* __restrict__ Wg,
                           unsigned short* __restrict__ Wsb) {
  int i = blockIdx.x * 256 + threadIdx.x;   // 4*16384
  int r = i >> 14, rem = i & 16383, j = rem >> 7, c = rem & 127;
  Wsb[i] = f2bf(rels_i[r * DD + c] * Wg[c * DD + j]);
}

// Wab = bf16( attn_w_in (3*16384) || attn_wout (16384) || fusion_w (16384) ), all [j][c]
__global__ void conv_w(const float* __restrict__ w_in, const float* __restrict__ w_out,
                       const float* __restrict__ w_fus, unsigned short* __restrict__ Wab) {
  int i = blockIdx.x * 256 + threadIdx.x;   // 5*16384
  float v = (i < 49152) ? w_in[i] : (i < 65536 ? w_out[i - 49152] : w_fus[i - 65536]);
  Wab[i] = f2bf(v);
}

// fp32 -> bf16, 4 elems/thread
__global__ void conv_f2b(const float* __restrict__ in, unsigned* __restrict__ out2, size_t n4) {
  size_t i = (size_t)blockIdx.x * 256 + threadIdx.x;
  if (i < n4) {
    float4 v = ((const float4*)in)[i];
    out2[i * 2]     = pack2(v.x, v.y);
    out2[i * 2 + 1] = pack2(v.z, v.w);
  }
}

// ---------------- CSR build ----------------

__global__ void count_deg(const int* __restrict__ ei, int* __restrict__ deg, int N, int E) {
  int r = blockIdx.y;
  int e = blockIdx.x * 256 + threadIdx.x;
  if (e < E) {
    int dst = ei[(size_t)edge_perm(r) * 2 * E + E + e];
    atomicAdd(deg + (size_t)r * N + dst, 1);
  }
}

__global__ void finalize_dinv(const int* __restrict__ deg, float* __restrict__ dinv, int total) {
  int i = blockIdx.x * 256 + threadIdx.x;
  if (i < total) dinv[i] = rsqrtf((float)deg[i] + 1.0f);
}

__global__ void scan_block(const int* __restrict__ deg, int* __restrict__ excl,
                           int* __restrict__ bsums, int n) {
  __shared__ int sh[256];
  int i = blockIdx.x * 256 + threadIdx.x;
  int v = (i < n) ? deg[i] : 0;
  sh[threadIdx.x] = v;
  __syncthreads();
  for (int st = 1; st < 256; st <<= 1) {
    int t = (threadIdx.x >= st) ? sh[threadIdx.x - st] : 0;
    __syncthreads();
    sh[threadIdx.x] += t;
    __syncthreads();
  }
  if (i < n) excl[i] = sh[threadIdx.x] - v;
  if (threadIdx.x == 255) bsums[blockIdx.x] = sh[255];
}

__global__ void scan_sums(int* __restrict__ bsums, int nb) {
  __shared__ int sh[1024];
  int v = (threadIdx.x < nb) ? bsums[threadIdx.x] : 0;
  sh[threadIdx.x] = v;
  __syncthreads();
  for (int st = 1; st < 1024; st <<= 1) {
    int t = (threadIdx.x >= st) ? sh[threadIdx.x - st] : 0;
    __syncthreads();
    sh[threadIdx.x] += t;
    __syncthreads();
  }
  if (threadIdx.x < nb) bsums[threadIdx.x] = sh[threadIdx.x] - v;  // exclusive
}

__global__ void scan_add(int* __restrict__ excl, int* __restrict__ cursor,
                         const int* __restrict__ bsums, int n) {
  int i = blockIdx.x * 256 + threadIdx.x;
  if (i < n) {
    int o = excl[i] + bsums[blockIdx.x];
    excl[i] = o;
    cursor[i] = o;
  }
}

__global__ void fill_edges(const int* __restrict__ ei, int* __restrict__ cursor,
                           int* __restrict__ srcbuf, int N, int E) {
  int r = blockIdx.y;
  int e = blockIdx.x * 256 + threadIdx.x;
  if (e < E) {
    const int* base = ei + (size_t)edge_perm(r) * 2 * E;
    int src = base[e], dst = base[E + e];
    int pos = atomicAdd(&cursor[r * N + dst], 1);
    srcbuf[pos] = r * N + src;   // global row index into Bs
  }
}

// ---------------- MFMA GEMM: Y[M,128] = X[M,128] @ Wt^T, z-batched x4 ----------------
// X bf16 row-major [M][128] (slice pointer); Wt bf16 [n=j][k=c] (128x128).
// Y is the slice pointer -> store at row*DD+col (NO extra z offset; that was the r3 bug).
// MODE 0: out bf16 = y * dinv[z*M+row]           (GCN messages; no bias)
// MODE 1: out bf16 = y + bias[col]               (QKV / out-proj)
// MODE 2: no store; s += leaky(y+bias[col])*fq[col]; block-reduce -> atomicAdd(S+z)
template <int MODE>
__global__ __launch_bounds__(256) void gemm_mfma(PtrB4 xs, PtrB4 wz, OutB4 ys,
                                                 const float* __restrict__ bias,
                                                 const float* __restrict__ dinv,
                                                 const float* __restrict__ fq,
                                                 float* __restrict__ S, int M) {
  int z = blockIdx.y;
  const unsigned short* __restrict__ X = xs.p[z];
  const unsigned short* __restrict__ W = wz.p[z];
  unsigned short* __restrict__ Y = ys.p[z];
  int tid = threadIdx.x;
  int wave = tid >> 6, lane = tid & 63;
  int r16 = lane & 15, kgrp = lane >> 4;
  int rowbase = blockIdx.x * 64 + wave * 16;
  int rowA = rowbase + r16;
  int rowAc = rowA < M ? rowA : M - 1;

  f32x4 acc[8];
#pragma unroll
  for (int nt = 0; nt < 8; ++nt)
#pragma unroll
    for (int j = 0; j < 4; ++j) acc[nt][j] = 0.f;

  const unsigned short* Xp = X + (size_t)rowAc * DD + kgrp * 8;
#pragma unroll
  for (int s = 0; s < 4; ++s) {
    short8 a = *(const short8*)(Xp + s * 32);
#pragma unroll
    for (int nt = 0; nt < 8; ++nt) {
      short8 b = *(const short8*)(W + ((nt * 16 + r16) << 7) + s * 32 + kgrp * 8);
      acc[nt] = __builtin_amdgcn_mfma_f32_16x16x32_bf16(a, b, acc[nt], 0, 0, 0);
    }
  }

  // D layout: col = lane&15, row = (lane>>4)*4 + i
  float ss = 0.f;
  float dv[4];
  if (MODE == 0) {
#pragma unroll
    for (int i = 0; i < 4; ++i) {
      int row = rowbase + kgrp * 4 + i;
      dv[i] = dinv[(size_t)z * M + (row < M ? row : 0)];
    }
  }
#pragma unroll
  for (int nt = 0; nt < 8; ++nt) {
    int col = nt * 16 + r16;
    float bb = (MODE >= 1) ? bias[col] : 0.f;
#pragma unroll
    for (int i = 0; i < 4; ++i) {
      int row = rowbase + kgrp * 4 + i;
      if (row < M) {
        float y = acc[nt][i] + bb;
        if (MODE == 0) {
          Y[(size_t)row * DD + col] = f2bf(y * dv[i]);
        } else if (MODE == 1) {
          Y[(size_t)row * DD + col] = f2bf(y);
        } else {
          float v = y > 0.f ? y : 0.01f * y;
          ss += v * fq[col];
        }
      }
    }
  }
  if (MODE == 2) {
    __shared__ float red[256];
    red[tid] = ss;
    __syncthreads();
    for (int st = 128; st > 0; st >>= 1) {
      if (tid < st) red[tid] += red[tid + st];
      __syncthreads();
    }
    if (tid == 0) atomicAdd(S + z, red[0]);
  }
}

// ---------------- GCN aggregation: CSR gather, bf16 in/out, unroll x4 ----------------
__global__ __launch_bounds__(256) void gather_agg(const int* __restrict__ srcbuf,
                                                  const int* __restrict__ offs,
                                                  const int* __restrict__ deg,
                                                  const float* __restrict__ dinv,
                                                  const unsigned* __restrict__ Bs2,
                                                  const float* __restrict__ bias,
                                                  unsigned* __restrict__ Ab2, int N4) {
  int rn = blockIdx.x * 4 + (threadIdx.x >> 6);
  if (rn >= N4) return;
  int lane = threadIdx.x & 63;
  int st = offs[rn], cnt = deg[rn];
  unsigned u = Bs2[(size_t)rn * 64 + lane];        // self message
  float a0 = bf_lo(u), a1 = bf_hi(u);
  int e = 0;
  for (; e + 4 <= cnt; e += 4) {
    int r0 = srcbuf[st + e], r1 = srcbuf[st + e + 1];
    int r2 = srcbuf[st + e + 2], r3 = srcbuf[st + e + 3];
    unsigned v0 = Bs2[(size_t)r0 * 64 + lane];
    unsigned v1 = Bs2[(size_t)r1 * 64 + lane];
    unsigned v2 = Bs2[(size_t)r2 * 64 + lane];
    unsigned v3 = Bs2[(size_t)r3 * 64 + lane];
    a0 += bf_lo(v0) + bf_lo(v1) + bf_lo(v2) + bf_lo(v3);
    a1 += bf_hi(v0) + bf_hi(v1) + bf_hi(v2) + bf_hi(v3);
  }
  for (; e < cnt; ++e) {
    unsigned v = Bs2[(size_t)srcbuf[st + e] * 64 + lane];
    a0 += bf_lo(v); a1 += bf_hi(v);
  }
  float dvv = dinv[rn];
  int c = lane * 2;
  Ab2[(size_t)rn * 64 + lane] = pack2(a0 * dvv + bias[c], a1 * dvv + bias[c + 1]);
}

// ---------------- batchnorm ----------------

__global__ void bn_stats(const unsigned* __restrict__ Ab2, float* __restrict__ sums, int N) {
  int r = blockIdx.y;
  int lane = threadIdx.x & 63, grp = threadIdx.x >> 6;
  float s0 = 0.f, q0 = 0.f, s1 = 0.f, q1 = 0.f;
  const unsigned* base = Ab2 + (size_t)r * N * 64;
  for (int n = blockIdx.x * 4 + grp; n < N; n += gridDim.x * 4) {
    unsigned u = base[(size_t)n * 64 + lane];
    float a = bf_lo(u), b = bf_hi(u);
    s0 += a; q0 += a * a; s1 += b; q1 += b * b;
  }
  __shared__ float sh[4][64][4];
  sh[grp][lane][0] = s0; sh[grp][lane][1] = q0; sh[grp][lane][2] = s1; sh[grp][lane][3] = q1;
  __syncthreads();
  if (grp == 0) {
#pragma unroll
    for (int g = 1; g < 4; ++g) {
      s0 += sh[g][lane][0]; q0 += sh[g][lane][1]; s1 += sh[g][lane][2]; q1 += sh[g][lane][3];
    }
    int c0 = lane * 2;
    atomicAdd(sums + (r * DD + c0) * 2, s0);
    atomicAdd(sums + (r * DD + c0) * 2 + 1, q0);
    atomicAdd(sums + (r * DD + c0 + 1) * 2, s1);
    atomicAdd(sums + (r * DD + c0 + 1) * 2 + 1, q1);
  }
}

__global__ void bn_final(const float* __restrict__ sums, const float* __restrict__ gamma,
                         const float* __restrict__ beta, float* __restrict__ ss, int N) {
  int t = threadIdx.x;       // 512 = r*128+c
  int c = t & 127;
  float mu = sums[t * 2] / N;
  float var = sums[t * 2 + 1] / N - mu * mu;
  float sc = gamma[c] * rsqrtf(var + 1e-5f);
  ss[t * 2] = sc;
  ss[t * 2 + 1] = beta[c] - mu * sc;
}

// emb' = base + leaky(Ab*sc+sh); write C fp32 (residual carrier) + Xb bf16 (next GEMM input)
__global__ void bn_update(float* __restrict__ C, const unsigned* __restrict__ Ab2,
                          const float* __restrict__ ss, const float* __restrict__ base0,
                          unsigned* __restrict__ Xb2, int N) {
  size_t p = (size_t)blockIdx.x * 256 + threadIdx.x;   // pair index over 4*N*64
  size_t tot = (size_t)4 * N * 64;
  if (p >= tot) return;
  size_t rn = p >> 6;
  int r = (int)(rn / (size_t)N);
  int c0 = ((int)(p & 63)) * 2;
  unsigned u = Ab2[p];
  float x0 = bf_lo(u) * ss[(r * DD + c0) * 2] + ss[(r * DD + c0) * 2 + 1];
  float x1 = bf_hi(u) * ss[(r * DD + c0 + 1) * 2] + ss[(r * DD + c0 + 1) * 2 + 1];
  x0 = x0 > 0.f ? x0 : 0.01f * x0;
  x1 = x1 > 0.f ? x1 : 0.01f * x1;
  float2 bb;
  if (base0) bb = *(const float2*)(base0 + (p - (size_t)r * N * 64) * 2);
  else       bb = *(const float2*)(C + p * 2);
  float e0 = bb.x + x0, e1 = bb.y + x1;
  *(float2*)(C + p * 2) = make_float2(e0, e1);
  Xb2[p] = pack2(e0, e1);
}

// ---------------- attention ----------------

__global__ void attn_scores(const unsigned short* __restrict__ Q,
                            const unsigned short* __restrict__ K,
                            float* __restrict__ P, int N) {
  int sb = threadIdx.x >> 6;                // 4 nodes / block
  int node = blockIdx.x * 4 + sb;
  int lane = threadIdx.x & 63;
  __shared__ float qs[4][4][132], ks[4][4][132];
  if (node < N) {
    int l = lane >> 4, c8 = (lane & 15) * 8;
    uint4 qv = *(const uint4*)(Q + ((size_t)l * N + node) * DD + c8);
    uint4 kv = *(const uint4*)(K + ((size_t)l * N + node) * DD + c8);
    unsigned qa[4] = {qv.x, qv.y, qv.z, qv.w};
    unsigned ka[4] = {kv.x, kv.y, kv.z, kv.w};
#pragma unroll
    for (int j = 0; j < 4; ++j) {
      qs[sb][l][c8 + 2 * j]     = bf_lo(qa[j]);
      qs[sb][l][c8 + 2 * j + 1] = bf_hi(qa[j]);
      ks[sb][l][c8 + 2 * j]     = bf_lo(ka[j]);
      ks[sb][l][c8 + 2 * j + 1] = bf_hi(ka[j]);
    }
  }
  __syncthreads();
  if (node < N) {
    int h = lane >> 4, l = (lane >> 2) & 3, m = lane & 3;
    const float* qp = &qs[sb][l][h * 32];
    const float* kp = &ks[sb][m][h * 32];
    float s = 0.f;
#pragma unroll
    for (int k2 = 0; k2 < 32; ++k2) s += qp[k2] * kp[k2];
    s *= 0.17677669529663687f;              // 1/sqrt(32)
    float mx = s;
    mx = fmaxf(mx, __shfl_xor(mx, 1));
    mx = fmaxf(mx, __shfl_xor(mx, 2));
    float e = expf(s - mx);
    float sum = e;
    sum += __shfl_xor(sum, 1);
    sum += __shfl_xor(sum, 2);
    P[(size_t)node * 64 + lane] = e / sum;  // [node][h][l][m]
  }
}

__global__ void attn_apply(const float* __restrict__ P, const unsigned* __restrict__ Vb2,
                           unsigned* __restrict__ Ob2, int N) {
  int node = blockIdx.x * 4 + (threadIdx.x >> 6);
  int lane = threadIdx.x & 63;
  if (node >= N) return;
  int c0 = lane * 2, h = c0 >> 5;
  const float* pp = P + (size_t)node * 64 + h * 16;
  unsigned v0 = Vb2[((size_t)0 * N + node) * 64 + lane];
  unsigned v1 = Vb2[((size_t)1 * N + node) * 64 + lane];
  unsigned v2 = Vb2[((size_t)2 * N + node) * 64 + lane];
  unsigned v3 = Vb2[((size_t)3 * N + node) * 64 + lane];
  float vl[4] = {bf_lo(v0), bf_lo(v1), bf_lo(v2), bf_lo(v3)};
  float vh[4] = {bf_hi(v0), bf_hi(v1), bf_hi(v2), bf_hi(v3)};
#pragma unroll
  for (int l = 0; l < 4; ++l) {
    float p0 = pp[l * 4], p1 = pp[l * 4 + 1], p2 = pp[l * 4 + 2], p3 = pp[l * 4 + 3];
    float ol = p0 * vl[0] + p1 * vl[1] + p2 * vl[2] + p3 * vl[3];
    float oh = p0 * vh[0] + p1 * vh[1] + p2 * vh[2] + p3 * vh[3];
    Ob2[((size_t)l * N + node) * 64 + lane] = pack2(ol, oh);
  }
}

// f[l] = a[l]*proj[l] + (1-a[l])*Ab[p[l]], p = {3,0,2,1}; in-place over proj (fb==Pj)
__global__ void blend(unsigned* __restrict__ fb, const unsigned* __restrict__ Ab,
                      const float* __restrict__ alphas, int N) {
  size_t per = (size_t)N * 16;               // uint4s per slice (N*128/8)
  size_t i = (size_t)blockIdx.x * 256 + threadIdx.x;
  if (i >= 4 * per) return;
  int l = (int)(i / per);
  int pl = (l == 0) ? 3 : (l == 1) ? 0 : (l == 2) ? 2 : 1;
  float a = alphas[l], na = 1.f - a;
  uint4 pj = ((const uint4*)fb)[i];
  uint4 st = ((const uint4*)Ab)[(size_t)pl * per + (i - (size_t)l * per)];
  unsigned po[4] = {pj.x, pj.y, pj.z, pj.w};
  unsigned so[4] = {st.x, st.y, st.z, st.w};
  uint4 o;
  unsigned* oo = &o.x;
#pragma unroll
  for (int j = 0; j < 4; ++j)
    oo[j] = pack2(a * bf_lo(po[j]) + na * bf_lo(so[j]),
                  a * bf_hi(po[j]) + na * bf_hi(so[j]));
  ((uint4*)fb)[i] = o;
}

// w = softmax([S(f0),S(f1),S(f3),S(f2)]);  coef[l] multiplies f[l]: coef = [w0,w1,w3,w2]
__global__ void wcoef(const float* __restrict__ S, float* __restrict__ coef, int N) {
  if (threadIdx.x == 0) {
    float v0 = S[0] / N, v1 = S[1] / N, v2 = S[3] / N, v3 = S[2] / N;
    float mx = fmaxf(fmaxf(v0, v1), fmaxf(v2, v3));
    float e0 = expf(v0 - mx), e1 = expf(v1 - mx), e2 = expf(v2 - mx), e3 = expf(v3 - mx);
    float inv = 1.f / (e0 + e1 + e2 + e3);
    coef[0] = e0 * inv; coef[1] = e1 * inv; coef[2] = e3 * inv; coef[3] = e2 * inv;
  }
}

__device__ __forceinline__ float bfat(uint2 u, int j) {
  unsigned w = (j < 2) ? u.x : u.y;
  return (j & 1) ? bf_hi(w) : bf_lo(w);
}

// region = sum coef[l]*f[l]; outputs: region, region*rels3[{3,0,1,2}]
__global__ void final_out(const unsigned short* __restrict__ fb, const float* __restrict__ coef,
                          const float* __restrict__ rels3, float* __restrict__ out, int N) {
  size_t NK = (size_t)N * DD;
  size_t i4 = (size_t)blockIdx.x * 256 + threadIdx.x;  // 4-elem groups
  if (i4 >= NK / 4) return;
  size_t g = i4 * 4;
  int c = (int)(g & 127);
  float c0 = coef[0], c1 = coef[1], c2 = coef[2], c3 = coef[3];
  uint2 u0 = *(const uint2*)(fb + g);
  uint2 u1 = *(const uint2*)(fb + NK + g);
  uint2 u2 = *(const uint2*)(fb + 2 * NK + g);
  uint2 u3 = *(const uint2*)(fb + 3 * NK + g);
  float4 reg4, o1, o2, o3, o4;
  float* rp = &reg4.x; float* p1 = &o1.x; float* p2 = &o2.x; float* p3 = &o3.x; float* p4 = &o4.x;
#pragma unroll
  for (int j = 0; j < 4; ++j) {
    float region = c0 * bfat(u0, j) + c1 * bfat(u1, j) + c2 * bfat(u2, j) + c3 * bfat(u3, j);
    rp[j] = region;
    p1[j] = region * rels3[3 * DD + c + j];
    p2[j] = region * rels3[0 * DD + c + j];
    p3[j] = region * rels3[1 * DD + c + j];
    p4[j] = region * rels3[2 * DD + c + j];
  }
  *(float4*)(out + g) = reg4;
  *(float4*)(out + NK + g) = o1;
  *(float4*)(out + 2 * NK + g) = o2;
  *(float4*)(out + 3 * NK + g) = o3;
  *(float4*)(out + 4 * NK + g) = o4;
}

// ---------------- host ----------------

extern "C" void kernel_launch(void* const* d_in, const int* in_sizes, int n_in,
                              void* d_out, int out_size, void* d_ws, size_t ws_size,
                              hipStream_t stream) {
  const float* features  = (const float*)d_in[0];
  const float* rel_emb   = (const float*)d_in[1];
  const int*   edge_idx  = (const int*)d_in[2];
  const float* W_gcn     = (const float*)d_in[3];
  const float* b_gcn     = (const float*)d_in[4];
  const float* bn_gamma  = (const float*)d_in[5];
  const float* bn_beta   = (const float*)d_in[6];
  const float* W_rt      = (const float*)d_in[7];
  const float* b_rt      = (const float*)d_in[8];
  const float* attn_w_in = (const float*)d_in[9];
  const float* attn_b_in = (const float*)d_in[10];
  const float* attn_wout = (const float*)d_in[11];
  const float* attn_bout = (const float*)d_in[12];
  const float* alphas    = (const float*)d_in[13];
  const float* fusion_q  = (const float*)d_in[14];
  const float* fusion_w  = (const float*)d_in[15];
  const float* fusion_b  = (const float*)d_in[16];

  int N = in_sizes[0] / DD;                  // 50000
  int E = in_sizes[2] / (2 * NREL);          // 400000
  size_t NK = (size_t)N * DD;
  int N4 = 4 * N;

  unsigned short* Xb = (unsigned short*)d_ws;            // 4*NK bf16
  unsigned short* Bs = Xb + 4 * NK;                      // 4*NK
  unsigned short* Ab = Bs + 4 * NK;                      // 4*NK
  unsigned short* Ub = Ab + 4 * NK;                      // 4*NK
  float* dinv  = (float*)(Ub + 4 * NK);                  // 4*N
  float* P     = dinv + N4;                              // N*64
  unsigned short* Wgcnb = (unsigned short*)(P + (size_t)N * 64);  // 4*16384
  unsigned short* Wab   = Wgcnb + 4 * DD * DD;           // 5*16384
  float* rels  = (float*)(Wab + 5 * DD * DD);            // 4 stages * 512
  float* bnsum = rels + 4 * 512;                         // 1024
  float* bnss  = bnsum + 1024;                           // 1024
  float* S     = bnss + 1024;                            // 4
  float* coef  = S + 4;                                  // 4
  int* deg_i   = (int*)(coef + 4);                       // 4*N
  int* offs    = deg_i + N4;                             // 4*N
  int* cur     = offs + N4;                              // 4*N
  int* bsums   = cur + N4;                               // 1024
  int* srcb    = bsums + 1024;                           // 4*E
  float* C     = (float*)d_out;                          // fp32 embs residual (slices 0..3)

  size_t needed = (size_t)((char*)(srcb + 4 * E) - (char*)d_ws);
  if (ws_size < needed) {
    fprintf(stderr, "kernel_launch: ws too small (%zu < %zu)\n", ws_size, needed);
    return;
  }

  int gemmGrid = (N + 63) / 64;
  int scanBlocks = (N4 + 255) / 256;
  int egrid = (E + 255) / 256;

  // ---- CSR build (edges fixed across layers) ----
  hipMemsetAsync(deg_i, 0, (size_t)N4 * sizeof(int), stream);
  count_deg<<<dim3(egrid, 4), 256, 0, stream>>>(edge_idx, deg_i, N, E);
  finalize_dinv<<<scanBlocks, 256, 0, stream>>>(deg_i, dinv, N4);
  scan_block<<<scanBlocks, 256, 0, stream>>>(deg_i, offs, bsums, N4);
  scan_sums<<<1, 1024, 0, stream>>>(bsums, scanBlocks);
  scan_add<<<scanBlocks, 256, 0, stream>>>(offs, cur, bsums, N4);
  fill_edges<<<dim3(egrid, 4), 256, 0, stream>>>(edge_idx, cur, srcb, N, E);

  rels_init<<<1, 512, 0, stream>>>(rel_emb, rels);
  conv_w<<<5 * 16384 / 256, 256, 0, stream>>>(attn_w_in, attn_wout, fusion_w, Wab);
  conv_f2b<<<(int)(NK / 4 / 256), 256, 0, stream>>>(features, (unsigned*)Xb, NK / 4);

  // ---- GCN layers ----
  PtrB4 xs, wz; OutB4 ys;
  const float* dummy = nullptr;
  for (int i = 0; i < 3; ++i) {
    scale_w_bf<<<256, 256, 0, stream>>>(rels + i * 512, W_gcn + (size_t)i * DD * DD, Wgcnb);
    for (int r = 0; r < 4; ++r) {
      xs.p[r] = (i == 0) ? Xb : (Xb + (size_t)r * NK);  // layer0: all rels share bf16(features)
      wz.p[r] = Wgcnb + (size_t)r * DD * DD;
      ys.p[r] = Bs + (size_t)r * NK;
    }
    gemm_mfma<0><<<dim3(gemmGrid, 4), 256, 0, stream>>>(xs, wz, ys, dummy, dinv, dummy, nullptr, N);
    gather_agg<<<(N4 + 3) / 4, 256, 0, stream>>>(srcb, offs, deg_i, dinv, (const unsigned*)Bs,
                                                 b_gcn + i * DD, (unsigned*)Ab, N4);
    if (i < 2) {
      hipMemsetAsync(bnsum, 0, 1024 * sizeof(float), stream);
      bn_stats<<<dim3(128, 4), 256, 0, stream>>>((const unsigned*)Ab, bnsum, N);
      bn_final<<<1, 512, 0, stream>>>(bnsum, bn_gamma + i * DD, bn_beta + i * DD, bnss, N);
      bn_update<<<(int)((2 * NK + 255) / 256), 256, 0, stream>>>(
          C, (const unsigned*)Ab, bnss, (i == 0) ? features : nullptr, (unsigned*)Xb, N);
    }
    rels_update<<<1, 512, 0, stream>>>(rels + i * 512, W_rt + (size_t)i * DD * DD,
                                       b_rt + i * DD, rels + (i + 1) * 512);
  }
  // Ab = final GCN outputs (bf16 stack source). Xb, Bs, Ub free. C dead.

  unsigned short* Qb = Xb;
  unsigned short* Kb = Bs;
  unsigned short* Vb = Ub;
  unsigned short* Ob = Xb;   // reuse after scores consume Qb
  unsigned short* Pj = Bs;   // reuse after scores consume Kb
  unsigned short* fb = Bs;   // blend runs in-place over Pj

  const int pstk[4] = {3, 0, 2, 1};
  PtrB4 stk, w4, fromO, fromF;
  OutB4 toQ, toK, toV, toP;
  for (int l = 0; l < 4; ++l) {
    stk.p[l] = Ab + (size_t)pstk[l] * NK;
    toQ.p[l] = Qb + (size_t)l * NK;
    toK.p[l] = Kb + (size_t)l * NK;
    toV.p[l] = Vb + (size_t)l * NK;
    toP.p[l] = Pj + (size_t)l * NK;
    fromO.p[l] = Ob + (size_t)l * NK;
    fromF.p[l] = fb + (size_t)l * NK;
  }

  for (int l = 0; l < 4; ++l) w4.p[l] = Wab;                        // Wq [j][c]
  gemm_mfma<1><<<dim3(gemmGrid, 4), 256, 0, stream>>>(stk, w4, toQ, attn_b_in, dummy, dummy, nullptr, N);
  for (int l = 0; l < 4; ++l) w4.p[l] = Wab + 16384;                // Wk
  gemm_mfma<1><<<dim3(gemmGrid, 4), 256, 0, stream>>>(stk, w4, toK, attn_b_in + DD, dummy, dummy, nullptr, N);
  attn_scores<<<(N + 3) / 4, 256, 0, stream>>>(Qb, Kb, P, N);
  for (int l = 0; l < 4; ++l) w4.p[l] = Wab + 2 * 16384;            // Wv
  gemm_mfma<1><<<dim3(gemmGrid, 4), 256, 0, stream>>>(stk, w4, toV, attn_b_in + 2 * DD, dummy, dummy, nullptr, N);
  attn_apply<<<(N + 3) / 4, 256, 0, stream>>>(P, (const unsigned*)Vb, (unsigned*)Ob, N);
  for (int l = 0; l < 4; ++l) w4.p[l] = Wab + 3 * 16384;            // Wo
  gemm_mfma<1><<<dim3(gemmGrid, 4), 256, 0, stream>>>(fromO, w4, toP, attn_bout, dummy, dummy, nullptr, N);
  blend<<<(int)((4 * NK / 8 + 255) / 256), 256, 0, stream>>>((unsigned*)fb, (const unsigned*)Ab, alphas, N);
  hipMemsetAsync(S, 0, 4 * sizeof(float), stream);
  for (int l = 0; l < 4; ++l) w4.p[l] = Wab + 4 * 16384;            // Wfus
  gemm_mfma<2><<<dim3(gemmGrid, 4), 256, 0, stream>>>(fromF, w4, toQ /*unused*/, fusion_b, dummy, fusion_q, S, N);
  wcoef<<<1, 64, 0, stream>>>(S, coef, N);
  final_out<<<(int)((NK / 4 + 255) / 256), 256, 0, stream>>>(fb, coef, rels + 3 * 512, (float*)d_out, N);
}

// Round 5
// 1305.705 us; speedup vs baseline: 3.0123x; 1.0263x over previous
//
#include <hip/hip_runtime.h>
#include <cstdio>

#define DD 128
#define NREL 4

using short8 = __attribute__((ext_vector_type(8))) short;
using f32x4  = __attribute__((ext_vector_type(4))) float;

struct PtrB4 { const unsigned short* p[4]; };
struct OutB4 { unsigned short* p[4]; };

// processing-order relation r uses edge_index/rel_emb row (r+3)&3  (perm = [3,0,1,2])
__device__ __forceinline__ int edge_perm(int r) { return (r + 3) & 3; }

__device__ __forceinline__ float bf_lo(unsigned u) { return __uint_as_float(u << 16); }
__device__ __forceinline__ float bf_hi(unsigned u) { return __uint_as_float(u & 0xffff0000u); }
__device__ __forceinline__ unsigned short f2bf(float f) {
  unsigned x = __float_as_uint(f);
  unsigned r = (x + 0x7fffu + ((x >> 16) & 1u)) >> 16;
  return (unsigned short)r;
}
__device__ __forceinline__ unsigned pack2(float a, float b) {
  return (unsigned)f2bf(a) | ((unsigned)f2bf(b) << 16);
}

// ---------------- init / weight prep ----------------

__global__ void rels_init(const float* __restrict__ rel_emb, float* __restrict__ rels) {
  int t = threadIdx.x;              // 512 = r*128 + c
  int r = t >> 7, c = t & 127;
  rels[t] = rel_emb[edge_perm(r) * DD + c];
}

__global__ void rels_update(const float* __restrict__ rin, const float* __restrict__ Wrt,
                            const float* __restrict__ brt, float* __restrict__ rout) {
  int t = threadIdx.x;  // 512 = r*128 + j
  int r = t >> 7, j = t & 127;
  float s = brt[j];
  const float* wr = Wrt + j * DD;
  const float* xr = rin + r * DD;
  for (int c = 0; c < DD; ++c) s += xr[c] * wr[c];
  rout[t] = s;
}

// Wsb[r][j][c] = bf16(rels[r][c] * Wg[c][j])  -- MFMA-B layout [n=j][k=c]
__global__ void scale_w_bf(const float* __restrict__ rels_i, const float* __restrict__ Wg,
                           unsigned short* __restrict__ Wsb) {
  int i = blockIdx.x * 256 + threadIdx.x;   // 4*16384
  int r = i >> 14, rem = i & 16383, j = rem >> 7, c = rem & 127;
  Wsb[i] = f2bf(rels_i[r * DD + c] * Wg[c * DD + j]);
}

// Wab = bf16( attn_w_in (3*16384) || attn_wout (16384) || fusion_w (16384) ), all [j][c]
__global__ void conv_w(const float* __restrict__ w_in, const float* __restrict__ w_out,
                       const float* __restrict__ w_fus, unsigned short* __restrict__ Wab) {
  int i = blockIdx.x * 256 + threadIdx.x;   // 5*16384
  float v = (i < 49152) ? w_in[i] : (i < 65536 ? w_out[i - 49152] : w_fus[i - 65536]);
  Wab[i] = f2bf(v);
}

// fp32 -> bf16, 4 elems/thread, replicated into 4 slices (residual base per relation)
__global__ void conv_f2b4(const float* __restrict__ in, unsigned* __restrict__ out2,
                          size_t n4, size_t slice_u) {
  size_t i = (size_t)blockIdx.x * 256 + threadIdx.x;
  if (i < n4) {
    float4 v = ((const float4*)in)[i];
    unsigned w0 = pack2(v.x, v.y), w1 = pack2(v.z, v.w);
#pragma unroll
    for (int r = 0; r < 4; ++r) {
      out2[r * slice_u + i * 2]     = w0;
      out2[r * slice_u + i * 2 + 1] = w1;
    }
  }
}

// ---------------- CSR build ----------------

__global__ void count_deg(const int* __restrict__ ei, int* __restrict__ deg, int N, int E) {
  int r = blockIdx.y;
  int e = blockIdx.x * 256 + threadIdx.x;
  if (e < E) {
    int dst = ei[(size_t)edge_perm(r) * 2 * E + E + e];
    atomicAdd(deg + (size_t)r * N + dst, 1);
  }
}

__global__ void finalize_dinv(const int* __restrict__ deg, float* __restrict__ dinv, int total) {
  int i = blockIdx.x * 256 + threadIdx.x;
  if (i < total) dinv[i] = rsqrtf((float)deg[i] + 1.0f);
}

__global__ void scan_block(const int* __restrict__ deg, int* __restrict__ excl,
                           int* __restrict__ bsums, int n) {
  __shared__ int sh[256];
  int i = blockIdx.x * 256 + threadIdx.x;
  int v = (i < n) ? deg[i] : 0;
  sh[threadIdx.x] = v;
  __syncthreads();
  for (int st = 1; st < 256; st <<= 1) {
    int t = (threadIdx.x >= st) ? sh[threadIdx.x - st] : 0;
    __syncthreads();
    sh[threadIdx.x] += t;
    __syncthreads();
  }
  if (i < n) excl[i] = sh[threadIdx.x] - v;
  if (threadIdx.x == 255) bsums[blockIdx.x] = sh[255];
}

__global__ void scan_sums(int* __restrict__ bsums, int nb) {
  __shared__ int sh[1024];
  int v = (threadIdx.x < nb) ? bsums[threadIdx.x] : 0;
  sh[threadIdx.x] = v;
  __syncthreads();
  for (int st = 1; st < 1024; st <<= 1) {
    int t = (threadIdx.x >= st) ? sh[threadIdx.x - st] : 0;
    __syncthreads();
    sh[threadIdx.x] += t;
    __syncthreads();
  }
  if (threadIdx.x < nb) bsums[threadIdx.x] = sh[threadIdx.x] - v;  // exclusive
}

__global__ void scan_add(int* __restrict__ excl, int* __restrict__ cursor,
                         const int* __restrict__ bsums, int n) {
  int i = blockIdx.x * 256 + threadIdx.x;
  if (i < n) {
    int o = excl[i] + bsums[blockIdx.x];
    excl[i] = o;
    cursor[i] = o;
  }
}

__global__ void fill_edges(const int* __restrict__ ei, int* __restrict__ cursor,
                           int* __restrict__ srcbuf, int N, int E) {
  int r = blockIdx.y;
  int e = blockIdx.x * 256 + threadIdx.x;
  if (e < E) {
    const int* base = ei + (size_t)edge_perm(r) * 2 * E;
    int src = base[e], dst = base[E + e];
    int pos = atomicAdd(&cursor[r * N + dst], 1);
    srcbuf[pos] = r * N + src;   // global row index into Bs
  }
}

// ---------------- MFMA GEMM: Y[M,128] = X[M,128] @ Wt^T, z-batched x4 ----------------
// X bf16 row-major [M][128] (slice ptr); Wt bf16 [n=j][k=c] (128x128); Y slice ptr.
// MODE 0: out bf16 = y * dinv[z*M+row]                         (GCN messages)
// MODE 1: out bf16 = y + bias[col]                             (QKV)
// MODE 3: out bf16 = alphas[z]*(y+bias) + (1-alphas[z])*stk    (out-proj + blend fused)
// MODE 2: no store; s += leaky(y+bias[col])*fq[col]; block-reduce -> atomicAdd(S+z)
template <int MODE>
__global__ __launch_bounds__(256) void gemm_mfma(PtrB4 xs, PtrB4 wz, OutB4 ys,
                                                 const float* __restrict__ bias,
                                                 const float* __restrict__ dinv,
                                                 const float* __restrict__ fq,
                                                 float* __restrict__ S,
                                                 PtrB4 stks,
                                                 const float* __restrict__ alphas,
                                                 int M) {
  int z = blockIdx.y;
  const unsigned short* __restrict__ X = xs.p[z];
  const unsigned short* __restrict__ W = wz.p[z];
  int tid = threadIdx.x;
  int wave = tid >> 6, lane = tid & 63;
  int r16 = lane & 15, kgrp = lane >> 4;
  int blockrow = blockIdx.x * 64;
  int rowbase = blockrow + wave * 16;
  int rowA = rowbase + r16;
  int rowAc = rowA < M ? rowA : M - 1;

  f32x4 acc[8];
#pragma unroll
  for (int nt = 0; nt < 8; ++nt)
#pragma unroll
    for (int j = 0; j < 4; ++j) acc[nt][j] = 0.f;

  const unsigned short* Xp = X + (size_t)rowAc * DD + kgrp * 8;
#pragma unroll
  for (int s = 0; s < 4; ++s) {
    short8 a = *(const short8*)(Xp + s * 32);
#pragma unroll
    for (int nt = 0; nt < 8; ++nt) {
      short8 b = *(const short8*)(W + ((nt * 16 + r16) << 7) + s * 32 + kgrp * 8);
      acc[nt] = __builtin_amdgcn_mfma_f32_16x16x32_bf16(a, b, acc[nt], 0, 0, 0);
    }
  }

  // D layout: col = lane&15 (within 16-tile), row = (lane>>4)*4 + i
  if constexpr (MODE == 2) {
    float ss = 0.f;
#pragma unroll
    for (int nt = 0; nt < 8; ++nt) {
      int col = nt * 16 + r16;
      float bb = bias[col];
#pragma unroll
      for (int i = 0; i < 4; ++i) {
        int row = rowbase + kgrp * 4 + i;
        if (row < M) {
          float y = acc[nt][i] + bb;
          float v = y > 0.f ? y : 0.01f * y;
          ss += v * fq[col];
        }
      }
    }
    __shared__ float red[256];
    red[tid] = ss;
    __syncthreads();
    for (int st = 128; st > 0; st >>= 1) {
      if (tid < st) red[tid] += red[tid + st];
      __syncthreads();
    }
    if (tid == 0) atomicAdd(S + z, red[0]);
  } else {
    // stage tile in LDS, then coalesced 64B/thread stores
    __shared__ __align__(16) unsigned short tile[64][DD + 8];
    float dv[4];
    if constexpr (MODE == 0) {
#pragma unroll
      for (int i = 0; i < 4; ++i) {
        int row = rowbase + kgrp * 4 + i;
        dv[i] = dinv[(size_t)z * M + (row < M ? row : 0)];
      }
    }
#pragma unroll
    for (int nt = 0; nt < 8; ++nt) {
      int col = nt * 16 + r16;
      float bb = (MODE == 1 || MODE == 3) ? bias[col] : 0.f;
#pragma unroll
      for (int i = 0; i < 4; ++i) {
        int wrow = wave * 16 + kgrp * 4 + i;
        float y = acc[nt][i] + bb;
        if constexpr (MODE == 0) y *= dv[i];
        tile[wrow][col] = f2bf(y);
      }
    }
    __syncthreads();
    int orow = tid >> 2, seg = tid & 3;       // 64B segment of a row
    int grow = blockrow + orow;
    if (grow < M) {
      unsigned short* Yp = ys.p[z] + (size_t)grow * DD + seg * 32;
      const unsigned short* tp = &tile[orow][seg * 32];
      if constexpr (MODE == 3) {
        float aa = alphas[z], na = 1.f - aa;
        const unsigned short* sp = stks.p[z] + (size_t)grow * DD + seg * 32;
#pragma unroll
        for (int k = 0; k < 4; ++k) {
          uint4 pv = *(const uint4*)(tp + k * 8);
          uint4 sv = *(const uint4*)(sp + k * 8);
          const unsigned* pw = &pv.x;
          const unsigned* sw = &sv.x;
          uint4 o; unsigned* ow = &o.x;
#pragma unroll
          for (int j = 0; j < 4; ++j)
            ow[j] = pack2(aa * bf_lo(pw[j]) + na * bf_lo(sw[j]),
                          aa * bf_hi(pw[j]) + na * bf_hi(sw[j]));
          *(uint4*)(Yp + k * 8) = o;
        }
      } else {
#pragma unroll
        for (int k = 0; k < 4; ++k)
          *(uint4*)(Yp + k * 8) = *(const uint4*)(tp + k * 8);
      }
    }
  }
}

// ---------------- GCN aggregation: CSR gather, bf16, unroll x8 ----------------
__global__ __launch_bounds__(256) void gather_agg(const int* __restrict__ srcbuf,
                                                  const int* __restrict__ offs,
                                                  const int* __restrict__ deg,
                                                  const float* __restrict__ dinv,
                                                  const unsigned* __restrict__ Bs2,
                                                  const float* __restrict__ bias,
                                                  unsigned* __restrict__ Ab2, int N4) {
  int rn = blockIdx.x * 4 + (threadIdx.x >> 6);
  if (rn >= N4) return;
  int lane = threadIdx.x & 63;
  int st = offs[rn], cnt = deg[rn];
  unsigned u = Bs2[(size_t)rn * 64 + lane];        // self message
  float a0 = bf_lo(u), a1 = bf_hi(u);
  int e = 0;
  for (; e + 8 <= cnt; e += 8) {
    int rr[8];
#pragma unroll
    for (int j = 0; j < 8; ++j) rr[j] = srcbuf[st + e + j];
    unsigned vv[8];
#pragma unroll
    for (int j = 0; j < 8; ++j) vv[j] = Bs2[(size_t)rr[j] * 64 + lane];
#pragma unroll
    for (int j = 0; j < 8; ++j) { a0 += bf_lo(vv[j]); a1 += bf_hi(vv[j]); }
  }
  if (e + 4 <= cnt) {
    int rr[4];
#pragma unroll
    for (int j = 0; j < 4; ++j) rr[j] = srcbuf[st + e + j];
    unsigned vv[4];
#pragma unroll
    for (int j = 0; j < 4; ++j) vv[j] = Bs2[(size_t)rr[j] * 64 + lane];
#pragma unroll
    for (int j = 0; j < 4; ++j) { a0 += bf_lo(vv[j]); a1 += bf_hi(vv[j]); }
    e += 4;
  }
  for (; e < cnt; ++e) {
    unsigned v = Bs2[(size_t)srcbuf[st + e] * 64 + lane];
    a0 += bf_lo(v); a1 += bf_hi(v);
  }
  float dvv = dinv[rn];
  int c = lane * 2;
  Ab2[(size_t)rn * 64 + lane] = pack2(a0 * dvv + bias[c], a1 * dvv + bias[c + 1]);
}

// ---------------- batchnorm ----------------

__global__ void bn_stats(const unsigned* __restrict__ Ab2, float* __restrict__ sums, int N) {
  int r = blockIdx.y;
  int lane = threadIdx.x & 63, grp = threadIdx.x >> 6;
  float s0 = 0.f, q0 = 0.f, s1 = 0.f, q1 = 0.f;
  const unsigned* base = Ab2 + (size_t)r * N * 64;
  for (int n = blockIdx.x * 4 + grp; n < N; n += gridDim.x * 4) {
    unsigned u = base[(size_t)n * 64 + lane];
    float a = bf_lo(u), b = bf_hi(u);
    s0 += a; q0 += a * a; s1 += b; q1 += b * b;
  }
  __shared__ float sh[4][64][4];
  sh[grp][lane][0] = s0; sh[grp][lane][1] = q0; sh[grp][lane][2] = s1; sh[grp][lane][3] = q1;
  __syncthreads();
  if (grp == 0) {
#pragma unroll
    for (int g = 1; g < 4; ++g) {
      s0 += sh[g][lane][0]; q0 += sh[g][lane][1]; s1 += sh[g][lane][2]; q1 += sh[g][lane][3];
    }
    int c0 = lane * 2;
    atomicAdd(sums + (r * DD + c0) * 2, s0);
    atomicAdd(sums + (r * DD + c0) * 2 + 1, q0);
    atomicAdd(sums + (r * DD + c0 + 1) * 2, s1);
    atomicAdd(sums + (r * DD + c0 + 1) * 2 + 1, q1);
  }
}

__global__ void bn_final(const float* __restrict__ sums, const float* __restrict__ gamma,
                         const float* __restrict__ beta, float* __restrict__ ss, int N) {
  int t = threadIdx.x;       // 512 = r*128+c
  int c = t & 127;
  float mu = sums[t * 2] / N;
  float var = sums[t * 2 + 1] / N - mu * mu;
  float sc = gamma[c] * rsqrtf(var + 1e-5f);
  ss[t * 2] = sc;
  ss[t * 2 + 1] = beta[c] - mu * sc;
}

// emb' = emb + leaky(Ab*sc+sh), in place on bf16 Xb
__global__ void bn_update(const unsigned* __restrict__ Ab2, const float* __restrict__ ss,
                          unsigned* __restrict__ Xb2, int N) {
  size_t p = (size_t)blockIdx.x * 256 + threadIdx.x;   // pair index over 4*N*64
  size_t tot = (size_t)4 * N * 64;
  if (p >= tot) return;
  size_t rn = p >> 6;
  int r = (int)(rn / (size_t)N);
  int c0 = ((int)(p & 63)) * 2;
  unsigned u = Ab2[p];
  float x0 = bf_lo(u) * ss[(r * DD + c0) * 2] + ss[(r * DD + c0) * 2 + 1];
  float x1 = bf_hi(u) * ss[(r * DD + c0 + 1) * 2] + ss[(r * DD + c0 + 1) * 2 + 1];
  x0 = x0 > 0.f ? x0 : 0.01f * x0;
  x1 = x1 > 0.f ? x1 : 0.01f * x1;
  unsigned b = Xb2[p];
  Xb2[p] = pack2(bf_lo(b) + x0, bf_hi(b) + x1);
}

// ---------------- attention ----------------

__global__ void attn_scores(const unsigned short* __restrict__ Q,
                            const unsigned short* __restrict__ K,
                            float* __restrict__ P, int N) {
  int sb = threadIdx.x >> 6;                // 4 nodes / block
  int node = blockIdx.x * 4 + sb;
  int lane = threadIdx.x & 63;
  __shared__ float qs[4][4][132], ks[4][4][132];
  if (node < N) {
    int l = lane >> 4, c8 = (lane & 15) * 8;
    uint4 qv = *(const uint4*)(Q + ((size_t)l * N + node) * DD + c8);
    uint4 kv = *(const uint4*)(K + ((size_t)l * N + node) * DD + c8);
    unsigned qa[4] = {qv.x, qv.y, qv.z, qv.w};
    unsigned ka[4] = {kv.x, kv.y, kv.z, kv.w};
#pragma unroll
    for (int j = 0; j < 4; ++j) {
      qs[sb][l][c8 + 2 * j]     = bf_lo(qa[j]);
      qs[sb][l][c8 + 2 * j + 1] = bf_hi(qa[j]);
      ks[sb][l][c8 + 2 * j]     = bf_lo(ka[j]);
      ks[sb][l][c8 + 2 * j + 1] = bf_hi(ka[j]);
    }
  }
  __syncthreads();
  if (node < N) {
    int h = lane >> 4, l = (lane >> 2) & 3, m = lane & 3;
    const float* qp = &qs[sb][l][h * 32];
    const float* kp = &ks[sb][m][h * 32];
    float s = 0.f;
#pragma unroll
    for (int k2 = 0; k2 < 32; ++k2) s += qp[k2] * kp[k2];
    s *= 0.17677669529663687f;              // 1/sqrt(32)
    float mx = s;
    mx = fmaxf(mx, __shfl_xor(mx, 1));
    mx = fmaxf(mx, __shfl_xor(mx, 2));
    float e = expf(s - mx);
    float sum = e;
    sum += __shfl_xor(sum, 1);
    sum += __shfl_xor(sum, 2);
    P[(size_t)node * 64 + lane] = e / sum;  // [node][h][l][m]
  }
}

__global__ void attn_apply(const float* __restrict__ P, const unsigned* __restrict__ Vb2,
                           unsigned* __restrict__ Ob2, int N) {
  int node = blockIdx.x * 4 + (threadIdx.x >> 6);
  int lane = threadIdx.x & 63;
  if (node >= N) return;
  int c0 = lane * 2, h = c0 >> 5;
  const float* pp = P + (size_t)node * 64 + h * 16;
  unsigned v0 = Vb2[((size_t)0 * N + node) * 64 + lane];
  unsigned v1 = Vb2[((size_t)1 * N + node) * 64 + lane];
  unsigned v2 = Vb2[((size_t)2 * N + node) * 64 + lane];
  unsigned v3 = Vb2[((size_t)3 * N + node) * 64 + lane];
  float vl[4] = {bf_lo(v0), bf_lo(v1), bf_lo(v2), bf_lo(v3)};
  float vh[4] = {bf_hi(v0), bf_hi(v1), bf_hi(v2), bf_hi(v3)};
#pragma unroll
  for (int l = 0; l < 4; ++l) {
    float p0 = pp[l * 4], p1 = pp[l * 4 + 1], p2 = pp[l * 4 + 2], p3 = pp[l * 4 + 3];
    float ol = p0 * vl[0] + p1 * vl[1] + p2 * vl[2] + p3 * vl[3];
    float oh = p0 * vh[0] + p1 * vh[1] + p2 * vh[2] + p3 * vh[3];
    Ob2[((size_t)l * N + node) * 64 + lane] = pack2(ol, oh);
  }
}

// w = softmax([S(f0),S(f1),S(f3),S(f2)]);  coef[l] multiplies f[l]: coef = [w0,w1,w3,w2]
__global__ void wcoef(const float* __restrict__ S, float* __restrict__ coef, int N) {
  if (threadIdx.x == 0) {
    float v0 = S[0] / N, v1 = S[1] / N, v2 = S[3] / N, v3 = S[2] / N;
    float mx = fmaxf(fmaxf(v0, v1), fmaxf(v2, v3));
    float e0 = expf(v0 - mx), e1 = expf(v1 - mx), e2 = expf(v2 - mx), e3 = expf(v3 - mx);
    float inv = 1.f / (e0 + e1 + e2 + e3);
    coef[0] = e0 * inv; coef[1] = e1 * inv; coef[2] = e3 * inv; coef[3] = e2 * inv;
  }
}

__device__ __forceinline__ float bfat(uint2 u, int j) {
  unsigned w = (j < 2) ? u.x : u.y;
  return (j & 1) ? bf_hi(w) : bf_lo(w);
}

// region = sum coef[l]*f[l]; outputs: region, region*rels3[{3,0,1,2}]
__global__ void final_out(const unsigned short* __restrict__ fb, const float* __restrict__ coef,
                          const float* __restrict__ rels3, float* __restrict__ out, int N) {
  size_t NK = (size_t)N * DD;
  size_t i4 = (size_t)blockIdx.x * 256 + threadIdx.x;  // 4-elem groups
  if (i4 >= NK / 4) return;
  size_t g = i4 * 4;
  int c = (int)(g & 127);
  float c0 = coef[0], c1 = coef[1], c2 = coef[2], c3 = coef[3];
  uint2 u0 = *(const uint2*)(fb + g);
  uint2 u1 = *(const uint2*)(fb + NK + g);
  uint2 u2 = *(const uint2*)(fb + 2 * NK + g);
  uint2 u3 = *(const uint2*)(fb + 3 * NK + g);
  float4 reg4, o1, o2, o3, o4;
  float* rp = &reg4.x; float* p1 = &o1.x; float* p2 = &o2.x; float* p3 = &o3.x; float* p4 = &o4.x;
#pragma unroll
  for (int j = 0; j < 4; ++j) {
    float region = c0 * bfat(u0, j) + c1 * bfat(u1, j) + c2 * bfat(u2, j) + c3 * bfat(u3, j);
    rp[j] = region;
    p1[j] = region * rels3[3 * DD + c + j];
    p2[j] = region * rels3[0 * DD + c + j];
    p3[j] = region * rels3[1 * DD + c + j];
    p4[j] = region * rels3[2 * DD + c + j];
  }
  *(float4*)(out + g) = reg4;
  *(float4*)(out + NK + g) = o1;
  *(float4*)(out + 2 * NK + g) = o2;
  *(float4*)(out + 3 * NK + g) = o3;
  *(float4*)(out + 4 * NK + g) = o4;
}

// ---------------- host ----------------

extern "C" void kernel_launch(void* const* d_in, const int* in_sizes, int n_in,
                              void* d_out, int out_size, void* d_ws, size_t ws_size,
                              hipStream_t stream) {
  const float* features  = (const float*)d_in[0];
  const float* rel_emb   = (const float*)d_in[1];
  const int*   edge_idx  = (const int*)d_in[2];
  const float* W_gcn     = (const float*)d_in[3];
  const float* b_gcn     = (const float*)d_in[4];
  const float* bn_gamma  = (const float*)d_in[5];
  const float* bn_beta   = (const float*)d_in[6];
  const float* W_rt      = (const float*)d_in[7];
  const float* b_rt      = (const float*)d_in[8];
  const float* attn_w_in = (const float*)d_in[9];
  const float* attn_b_in = (const float*)d_in[10];
  const float* attn_wout = (const float*)d_in[11];
  const float* attn_bout = (const float*)d_in[12];
  const float* alphas    = (const float*)d_in[13];
  const float* fusion_q  = (const float*)d_in[14];
  const float* fusion_w  = (const float*)d_in[15];
  const float* fusion_b  = (const float*)d_in[16];

  int N = in_sizes[0] / DD;                  // 50000
  int E = in_sizes[2] / (2 * NREL);          // 400000
  size_t NK = (size_t)N * DD;
  int N4 = 4 * N;

  unsigned short* Xb = (unsigned short*)d_ws;            // 4*NK bf16 (embs residual, in-place)
  unsigned short* Bs = Xb + 4 * NK;                      // 4*NK (messages / fb)
  unsigned short* Ab = Bs + 4 * NK;                      // 4*NK (gather out / stack)
  unsigned short* Ub = Ab + 4 * NK;                      // 4*NK (K / V)
  float* dinv  = (float*)(Ub + 4 * NK);                  // 4*N
  float* P     = dinv + N4;                              // N*64
  unsigned short* Wgcnb = (unsigned short*)(P + (size_t)N * 64);  // 4*16384
  unsigned short* Wab   = Wgcnb + 4 * DD * DD;           // 5*16384
  float* rels  = (float*)(Wab + 5 * DD * DD);            // 4 stages * 512
  float* bnsum = rels + 4 * 512;                         // 1024
  float* bnss  = bnsum + 1024;                           // 1024
  float* S     = bnss + 1024;                            // 4
  float* coef  = S + 4;                                  // 4
  int* deg_i   = (int*)(coef + 4);                       // 4*N
  int* offs    = deg_i + N4;                             // 4*N
  int* cur     = offs + N4;                              // 4*N
  int* bsums   = cur + N4;                               // 1024
  int* srcb    = bsums + 1024;                           // 4*E

  size_t needed = (size_t)((char*)(srcb + 4 * E) - (char*)d_ws);
  if (ws_size < needed) {
    fprintf(stderr, "kernel_launch: ws too small (%zu < %zu)\n", ws_size, needed);
    return;
  }

  int gemmGrid = (N + 63) / 64;
  int scanBlocks = (N4 + 255) / 256;
  int egrid = (E + 255) / 256;

  // ---- CSR build (edges fixed across layers) ----
  hipMemsetAsync(deg_i, 0, (size_t)N4 * sizeof(int), stream);
  count_deg<<<dim3(egrid, 4), 256, 0, stream>>>(edge_idx, deg_i, N, E);
  finalize_dinv<<<scanBlocks, 256, 0, stream>>>(deg_i, dinv, N4);
  scan_block<<<scanBlocks, 256, 0, stream>>>(deg_i, offs, bsums, N4);
  scan_sums<<<1, 1024, 0, stream>>>(bsums, scanBlocks);
  scan_add<<<scanBlocks, 256, 0, stream>>>(offs, cur, bsums, N4);
  fill_edges<<<dim3(egrid, 4), 256, 0, stream>>>(edge_idx, cur, srcb, N, E);

  rels_init<<<1, 512, 0, stream>>>(rel_emb, rels);
  conv_w<<<5 * 16384 / 256, 256, 0, stream>>>(attn_w_in, attn_wout, fusion_w, Wab);
  conv_f2b4<<<(int)((NK / 4 + 255) / 256), 256, 0, stream>>>(features, (unsigned*)Xb, NK / 4, NK / 2);

  PtrB4 dummyP; for (int l = 0; l < 4; ++l) dummyP.p[l] = nullptr;
  const float* dummy = nullptr;

  // ---- GCN layers ----
  PtrB4 xs, wz; OutB4 ys;
  for (int i = 0; i < 3; ++i) {
    scale_w_bf<<<256, 256, 0, stream>>>(rels + i * 512, W_gcn + (size_t)i * DD * DD, Wgcnb);
    for (int r = 0; r < 4; ++r) {
      xs.p[r] = Xb + (size_t)r * NK;
      wz.p[r] = Wgcnb + (size_t)r * DD * DD;
      ys.p[r] = Bs + (size_t)r * NK;
    }
    gemm_mfma<0><<<dim3(gemmGrid, 4), 256, 0, stream>>>(xs, wz, ys, dummy, dinv, dummy, nullptr, dummyP, dummy, N);
    gather_agg<<<(N4 + 3) / 4, 256, 0, stream>>>(srcb, offs, deg_i, dinv, (const unsigned*)Bs,
                                                 b_gcn + i * DD, (unsigned*)Ab, N4);
    if (i < 2) {
      hipMemsetAsync(bnsum, 0, 1024 * sizeof(float), stream);
      bn_stats<<<dim3(128, 4), 256, 0, stream>>>((const unsigned*)Ab, bnsum, N);
      bn_final<<<1, 512, 0, stream>>>(bnsum, bn_gamma + i * DD, bn_beta + i * DD, bnss, N);
      bn_update<<<(int)((2 * NK + 255) / 256), 256, 0, stream>>>(
          (const unsigned*)Ab, bnss, (unsigned*)Xb, N);
    }
    rels_update<<<1, 512, 0, stream>>>(rels + i * 512, W_rt + (size_t)i * DD * DD,
                                       b_rt + i * DD, rels + (i + 1) * 512);
  }
  // Ab = final GCN outputs (bf16 stack source). Xb, Bs, Ub free.

  unsigned short* Qb = Xb;
  unsigned short* Kb = Ub;
  unsigned short* Vb = Ub;   // V overwrites K after scores
  unsigned short* Ob = Xb;   // O overwrites Q after scores
  unsigned short* fb = Bs;   // blended f

  const int pstk[4] = {3, 0, 2, 1};
  PtrB4 stk, w4, fromO, fromF;
  OutB4 toQ, toK, toV, toF;
  for (int l = 0; l < 4; ++l) {
    stk.p[l] = Ab + (size_t)pstk[l] * NK;
    toQ.p[l] = Qb + (size_t)l * NK;
    toK.p[l] = Kb + (size_t)l * NK;
    toV.p[l] = Vb + (size_t)l * NK;
    toF.p[l] = fb + (size_t)l * NK;
    fromO.p[l] = Ob + (size_t)l * NK;
    fromF.p[l] = fb + (size_t)l * NK;
  }

  for (int l = 0; l < 4; ++l) w4.p[l] = Wab;                        // Wq [j][c]
  gemm_mfma<1><<<dim3(gemmGrid, 4), 256, 0, stream>>>(stk, w4, toQ, attn_b_in, dummy, dummy, nullptr, dummyP, dummy, N);
  for (int l = 0; l < 4; ++l) w4.p[l] = Wab + 16384;                // Wk
  gemm_mfma<1><<<dim3(gemmGrid, 4), 256, 0, stream>>>(stk, w4, toK, attn_b_in + DD, dummy, dummy, nullptr, dummyP, dummy, N);
  attn_scores<<<(N + 3) / 4, 256, 0, stream>>>(Qb, Kb, P, N);
  for (int l = 0; l < 4; ++l) w4.p[l] = Wab + 2 * 16384;            // Wv
  gemm_mfma<1><<<dim3(gemmGrid, 4), 256, 0, stream>>>(stk, w4, toV, attn_b_in + 2 * DD, dummy, dummy, nullptr, dummyP, dummy, N);
  attn_apply<<<(N + 3) / 4, 256, 0, stream>>>(P, (const unsigned*)Vb, (unsigned*)Ob, N);
  for (int l = 0; l < 4; ++l) w4.p[l] = Wab + 3 * 16384;            // Wo (+blend fused)
  gemm_mfma<3><<<dim3(gemmGrid, 4), 256, 0, stream>>>(fromO, w4, toF, attn_bout, dummy, dummy, nullptr, stk, alphas, N);
  hipMemsetAsync(S, 0, 4 * sizeof(float), stream);
  for (int l = 0; l < 4; ++l) w4.p[l] = Wab + 4 * 16384;            // Wfus (score fused)
  gemm_mfma<2><<<dim3(gemmGrid, 4), 256, 0, stream>>>(fromF, w4, toQ /*unused*/, fusion_b, dummy, fusion_q, S, dummyP, dummy, N);
  wcoef<<<1, 64, 0, stream>>>(S, coef, N);
  final_out<<<(int)((NK / 4 + 255) / 256), 256, 0, stream>>>(fb, coef, rels + 3 * 512, (float*)d_out, N);
}

// Round 6
// 1165.011 us; speedup vs baseline: 3.3761x; 1.1208x over previous
//
#include <hip/hip_runtime.h>
#include <cstdio>

#define DD 128
#define NREL 4

using short8 = __attribute__((ext_vector_type(8))) short;
using f32x4  = __attribute__((ext_vector_type(4))) float;

struct PtrB4 { const unsigned short* p[4]; };
struct OutB4 { unsigned short* p[4]; };

// processing-order relation r uses edge_index/rel_emb row (r+3)&3  (perm = [3,0,1,2])
__device__ __forceinline__ int edge_perm(int r) { return (r + 3) & 3; }

__device__ __forceinline__ float bf_lo(unsigned u) { return __uint_as_float(u << 16); }
__device__ __forceinline__ float bf_hi(unsigned u) { return __uint_as_float(u & 0xffff0000u); }
__device__ __forceinline__ float bfe(short s) {
  return __uint_as_float(((unsigned)(unsigned short)s) << 16);
}
__device__ __forceinline__ unsigned short f2bf(float f) {
  unsigned x = __float_as_uint(f);
  unsigned r = (x + 0x7fffu + ((x >> 16) & 1u)) >> 16;
  return (unsigned short)r;
}
__device__ __forceinline__ unsigned pack2(float a, float b) {
  return (unsigned)f2bf(a) | ((unsigned)f2bf(b) << 16);
}

// ---------------- init / weight prep ----------------

__global__ void rels_init(const float* __restrict__ rel_emb, float* __restrict__ rels) {
  int t = threadIdx.x;              // 512 = r*128 + c
  int r = t >> 7, c = t & 127;
  rels[t] = rel_emb[edge_perm(r) * DD + c];
}

__global__ void rels_update(const float* __restrict__ rin, const float* __restrict__ Wrt,
                            const float* __restrict__ brt, float* __restrict__ rout) {
  int t = threadIdx.x;  // 512 = r*128 + j
  int r = t >> 7, j = t & 127;
  float s = brt[j];
  const float* wr = Wrt + j * DD;
  const float* xr = rin + r * DD;
  for (int c = 0; c < DD; ++c) s += xr[c] * wr[c];
  rout[t] = s;
}

// Wsb[r][j][c] = bf16(rels[r][c] * Wg[c][j])  -- MFMA-B layout [n=j][k=c]
__global__ void scale_w_bf(const float* __restrict__ rels_i, const float* __restrict__ Wg,
                           unsigned short* __restrict__ Wsb) {
  int i = blockIdx.x * 256 + threadIdx.x;   // 4*16384
  int r = i >> 14, rem = i & 16383, j = rem >> 7, c = rem & 127;
  Wsb[i] = f2bf(rels_i[r * DD + c] * Wg[c * DD + j]);
}

// Wab = bf16( attn_w_in (3*16384) || attn_wout (16384) || fusion_w (16384) ), all [j][c]
__global__ void conv_w(const float* __restrict__ w_in, const float* __restrict__ w_out,
                       const float* __restrict__ w_fus, unsigned short* __restrict__ Wab) {
  int i = blockIdx.x * 256 + threadIdx.x;   // 5*16384
  float v = (i < 49152) ? w_in[i] : (i < 65536 ? w_out[i - 49152] : w_fus[i - 65536]);
  Wab[i] = f2bf(v);
}

// fp32 -> bf16 single slice
__global__ void conv_f2b(const float* __restrict__ in, unsigned* __restrict__ out2, size_t n4) {
  size_t i = (size_t)blockIdx.x * 256 + threadIdx.x;
  if (i < n4) {
    float4 v = ((const float4*)in)[i];
    out2[i * 2]     = pack2(v.x, v.y);
    out2[i * 2 + 1] = pack2(v.z, v.w);
  }
}

// ---------------- CSR build ----------------

__global__ void count_deg(const int* __restrict__ ei, int* __restrict__ deg, int N, int E) {
  int r = blockIdx.y;
  int base = blockIdx.x * 1024 + threadIdx.x;
  const int* dsts = ei + (size_t)edge_perm(r) * 2 * E + E;
#pragma unroll
  for (int k = 0; k < 4; ++k) {
    int e = base + k * 256;
    if (e < E) atomicAdd(deg + (size_t)r * N + dsts[e], 1);
  }
}

__global__ void finalize_dinv(const int* __restrict__ deg, float* __restrict__ dinv, int total) {
  int i = blockIdx.x * 256 + threadIdx.x;
  if (i < total) dinv[i] = rsqrtf((float)deg[i] + 1.0f);
}

__global__ void scan_block(const int* __restrict__ deg, int* __restrict__ excl,
                           int* __restrict__ bsums, int n) {
  __shared__ int sh[256];
  int i = blockIdx.x * 256 + threadIdx.x;
  int v = (i < n) ? deg[i] : 0;
  sh[threadIdx.x] = v;
  __syncthreads();
  for (int st = 1; st < 256; st <<= 1) {
    int t = (threadIdx.x >= st) ? sh[threadIdx.x - st] : 0;
    __syncthreads();
    sh[threadIdx.x] += t;
    __syncthreads();
  }
  if (i < n) excl[i] = sh[threadIdx.x] - v;
  if (threadIdx.x == 255) bsums[blockIdx.x] = sh[255];
}

__global__ void scan_sums(int* __restrict__ bsums, int nb) {
  __shared__ int sh[1024];
  int v = (threadIdx.x < nb) ? bsums[threadIdx.x] : 0;
  sh[threadIdx.x] = v;
  __syncthreads();
  for (int st = 1; st < 1024; st <<= 1) {
    int t = (threadIdx.x >= st) ? sh[threadIdx.x - st] : 0;
    __syncthreads();
    sh[threadIdx.x] += t;
    __syncthreads();
  }
  if (threadIdx.x < nb) bsums[threadIdx.x] = sh[threadIdx.x] - v;  // exclusive
}

__global__ void scan_add(int* __restrict__ excl, int* __restrict__ cursor,
                         const int* __restrict__ bsums, int n) {
  int i = blockIdx.x * 256 + threadIdx.x;
  if (i < n) {
    int o = excl[i] + bsums[blockIdx.x];
    excl[i] = o;
    cursor[i] = o;
  }
}

// 4 edges/thread: 4 independent atomic-returns in flight
__global__ void fill_edges(const int* __restrict__ ei, int* __restrict__ cursor,
                           int* __restrict__ srcbuf, int N, int E) {
  int r = blockIdx.y;
  int base = blockIdx.x * 1024 + threadIdx.x;
  const int* bp = ei + (size_t)edge_perm(r) * 2 * E;
  int s[4], d[4], pos[4];
#pragma unroll
  for (int k = 0; k < 4; ++k) {
    int e = base + k * 256;
    s[k] = (e < E) ? bp[e] : 0;
    d[k] = (e < E) ? bp[E + e] : 0;
  }
#pragma unroll
  for (int k = 0; k < 4; ++k) {
    int e = base + k * 256;
    if (e < E) pos[k] = atomicAdd(&cursor[r * N + d[k]], 1);
  }
#pragma unroll
  for (int k = 0; k < 4; ++k) {
    int e = base + k * 256;
    if (e < E) srcbuf[pos[k]] = r * N + s[k];
  }
}

// ---------------- GEMM kernels (16x16x32 bf16 MFMA, 64-row blocks) ----------------
// D layout: col = lane&15, row = (lane>>4)*4 + i

// Layer-0 message GEMM: X shared bf16 [M][128]; Bs[z][row] = bf16((X@Wz)*dinv[z*M+row])
__global__ __launch_bounds__(256) void gemm_msg(const unsigned short* __restrict__ X,
                                                PtrB4 wz, OutB4 ys,
                                                const float* __restrict__ dinv, int M) {
  int z = blockIdx.y;
  const unsigned short* __restrict__ W = wz.p[z];
  int tid = threadIdx.x;
  int wave = tid >> 6, lane = tid & 63;
  int r16 = lane & 15, kgrp = lane >> 4;
  int blockrow = blockIdx.x * 64;
  int rowbase = blockrow + wave * 16;
  int rowA = rowbase + r16;
  int rowAc = rowA < M ? rowA : M - 1;

  f32x4 acc[8];
#pragma unroll
  for (int nt = 0; nt < 8; ++nt)
#pragma unroll
    for (int j = 0; j < 4; ++j) acc[nt][j] = 0.f;

  const unsigned short* Xp = X + (size_t)rowAc * DD + kgrp * 8;
#pragma unroll
  for (int s = 0; s < 4; ++s) {
    short8 a = *(const short8*)(Xp + s * 32);
#pragma unroll
    for (int nt = 0; nt < 8; ++nt) {
      short8 b = *(const short8*)(W + ((nt * 16 + r16) << 7) + s * 32 + kgrp * 8);
      acc[nt] = __builtin_amdgcn_mfma_f32_16x16x32_bf16(a, b, acc[nt], 0, 0, 0);
    }
  }

  __shared__ __align__(16) unsigned short tile[64][DD + 8];
  float dv[4];
#pragma unroll
  for (int i = 0; i < 4; ++i) {
    int row = rowbase + kgrp * 4 + i;
    dv[i] = dinv[(size_t)z * M + (row < M ? row : 0)];
  }
#pragma unroll
  for (int nt = 0; nt < 8; ++nt) {
    int col = nt * 16 + r16;
#pragma unroll
    for (int i = 0; i < 4; ++i) {
      int wrow = wave * 16 + kgrp * 4 + i;
      tile[wrow][col] = f2bf(acc[nt][i] * dv[i]);
    }
  }
  __syncthreads();
  int orow = tid >> 2, seg = tid & 3;
  int grow = blockrow + orow;
  if (grow < M) {
    unsigned short* Yp = ys.p[z] + (size_t)grow * DD + seg * 32;
    const unsigned short* tp = &tile[orow][seg * 32];
#pragma unroll
    for (int k = 0; k < 4; ++k)
      *(uint4*)(Yp + k * 8) = *(const uint4*)(tp + k * 8);
  }
}

// Layers 1/2 fused GEMM: e = res + leaky(bn(Ab)); optional writeback of e; messages = (e@Wz)*dinv
template <int WB>
__global__ __launch_bounds__(256) void gemm_update(PtrB4 res, PtrB4 abs_, PtrB4 wz,
                                                   OutB4 xout, OutB4 ys,
                                                   const float* __restrict__ ssx,
                                                   const float* __restrict__ dinv, int M) {
  int z = blockIdx.y;
  const unsigned short* __restrict__ R = res.p[z];
  const unsigned short* __restrict__ A = abs_.p[z];
  const unsigned short* __restrict__ W = wz.p[z];
  int tid = threadIdx.x;

  __shared__ float ssc[DD], ssh[DD];
  if (tid < DD) {
    ssc[tid] = ssx[((size_t)z * DD + tid) * 2];
    ssh[tid] = ssx[((size_t)z * DD + tid) * 2 + 1];
  }
  __syncthreads();

  int wave = tid >> 6, lane = tid & 63;
  int r16 = lane & 15, kgrp = lane >> 4;
  int blockrow = blockIdx.x * 64;
  int rowbase = blockrow + wave * 16;
  int rowA = rowbase + r16;
  int rowAc = rowA < M ? rowA : M - 1;

  f32x4 acc[8];
#pragma unroll
  for (int nt = 0; nt < 8; ++nt)
#pragma unroll
    for (int j = 0; j < 4; ++j) acc[nt][j] = 0.f;

  const unsigned short* Rp = R + (size_t)rowAc * DD + kgrp * 8;
  const unsigned short* Ap = A + (size_t)rowAc * DD + kgrp * 8;
#pragma unroll
  for (int s = 0; s < 4; ++s) {
    int cbase = s * 32 + kgrp * 8;
    short8 rv = *(const short8*)(Rp + s * 32);
    short8 av = *(const short8*)(Ap + s * 32);
    short8 a;
#pragma unroll
    for (int j = 0; j < 8; ++j) {
      float x = bfe(av[j]) * ssc[cbase + j] + ssh[cbase + j];
      x = x > 0.f ? x : 0.01f * x;
      float e = bfe(rv[j]) + x;
      a[j] = (short)f2bf(e);
    }
    if (WB && rowA < M)
      *(short8*)(xout.p[z] + (size_t)rowA * DD + cbase) = a;
#pragma unroll
    for (int nt = 0; nt < 8; ++nt) {
      short8 b = *(const short8*)(W + ((nt * 16 + r16) << 7) + s * 32 + kgrp * 8);
      acc[nt] = __builtin_amdgcn_mfma_f32_16x16x32_bf16(a, b, acc[nt], 0, 0, 0);
    }
  }

  __shared__ __align__(16) unsigned short tile[64][DD + 8];
  float dv[4];
#pragma unroll
  for (int i = 0; i < 4; ++i) {
    int row = rowbase + kgrp * 4 + i;
    dv[i] = dinv[(size_t)z * M + (row < M ? row : 0)];
  }
#pragma unroll
  for (int nt = 0; nt < 8; ++nt) {
    int col = nt * 16 + r16;
#pragma unroll
    for (int i = 0; i < 4; ++i) {
      int wrow = wave * 16 + kgrp * 4 + i;
      tile[wrow][col] = f2bf(acc[nt][i] * dv[i]);
    }
  }
  __syncthreads();
  int orow = tid >> 2, seg = tid & 3;
  int grow = blockrow + orow;
  if (grow < M) {
    unsigned short* Yp = ys.p[z] + (size_t)grow * DD + seg * 32;
    const unsigned short* tp = &tile[orow][seg * 32];
#pragma unroll
    for (int k = 0; k < 4; ++k)
      *(uint4*)(Yp + k * 8) = *(const uint4*)(tp + k * 8);
  }
}

// QKV fused GEMM: one read of stk, three outputs (bias attn_b_in[3*128])
__global__ __launch_bounds__(256) void gemm_qkv(PtrB4 xs, const unsigned short* __restrict__ Wab,
                                                const float* __restrict__ bias3,
                                                OutB4 yq, OutB4 yk, OutB4 yv, int M) {
  int z = blockIdx.y;
  const unsigned short* __restrict__ X = xs.p[z];
  int tid = threadIdx.x;
  int wave = tid >> 6, lane = tid & 63;
  int r16 = lane & 15, kgrp = lane >> 4;
  int blockrow = blockIdx.x * 64;
  int rowbase = blockrow + wave * 16;
  int rowA = rowbase + r16;
  int rowAc = rowA < M ? rowA : M - 1;

  f32x4 acc[3][8];
#pragma unroll
  for (int o = 0; o < 3; ++o)
#pragma unroll
    for (int nt = 0; nt < 8; ++nt)
#pragma unroll
      for (int j = 0; j < 4; ++j) acc[o][nt][j] = 0.f;

  const unsigned short* Xp = X + (size_t)rowAc * DD + kgrp * 8;
#pragma unroll
  for (int s = 0; s < 4; ++s) {
    short8 a = *(const short8*)(Xp + s * 32);
#pragma unroll
    for (int o = 0; o < 3; ++o)
#pragma unroll
      for (int nt = 0; nt < 8; ++nt) {
        short8 b = *(const short8*)(Wab + o * 16384 + ((nt * 16 + r16) << 7) + s * 32 + kgrp * 8);
        acc[o][nt] = __builtin_amdgcn_mfma_f32_16x16x32_bf16(a, b, acc[o][nt], 0, 0, 0);
      }
  }

  __shared__ __align__(16) unsigned short tile[64][DD + 8];
  int orow = tid >> 2, seg = tid & 3;
  int grow = blockrow + orow;
#pragma unroll
  for (int o = 0; o < 3; ++o) {
#pragma unroll
    for (int nt = 0; nt < 8; ++nt) {
      int col = nt * 16 + r16;
      float bb = bias3[o * DD + col];
#pragma unroll
      for (int i = 0; i < 4; ++i) {
        int wrow = wave * 16 + kgrp * 4 + i;
        tile[wrow][col] = f2bf(acc[o][nt][i] + bb);
      }
    }
    __syncthreads();
    if (grow < M) {
      unsigned short* Yp = (o == 0 ? yq.p[z] : o == 1 ? yk.p[z] : yv.p[z]) +
                           (size_t)grow * DD + seg * 32;
      const unsigned short* tp = &tile[orow][seg * 32];
#pragma unroll
      for (int k = 0; k < 4; ++k)
        *(uint4*)(Yp + k * 8) = *(const uint4*)(tp + k * 8);
    }
    __syncthreads();
  }
}

// out-proj + blend + store f + chained fusion GEMM + leaky*fq score reduce
__global__ __launch_bounds__(256) void gemm_proj(PtrB4 xs, const unsigned short* __restrict__ Wo,
                                                 const unsigned short* __restrict__ Wf,
                                                 const float* __restrict__ bias,
                                                 PtrB4 stks, const float* __restrict__ alphas,
                                                 const float* __restrict__ fusion_b,
                                                 const float* __restrict__ fq,
                                                 OutB4 yf, float* __restrict__ S, int M) {
  int z = blockIdx.y;
  const unsigned short* __restrict__ X = xs.p[z];
  int tid = threadIdx.x;
  int wave = tid >> 6, lane = tid & 63;
  int r16 = lane & 15, kgrp = lane >> 4;
  int blockrow = blockIdx.x * 64;
  int rowbase = blockrow + wave * 16;
  int rowA = rowbase + r16;
  int rowAc = rowA < M ? rowA : M - 1;

  f32x4 acc[8];
#pragma unroll
  for (int nt = 0; nt < 8; ++nt)
#pragma unroll
    for (int j = 0; j < 4; ++j) acc[nt][j] = 0.f;

  const unsigned short* Xp = X + (size_t)rowAc * DD + kgrp * 8;
#pragma unroll
  for (int s = 0; s < 4; ++s) {
    short8 a = *(const short8*)(Xp + s * 32);
#pragma unroll
    for (int nt = 0; nt < 8; ++nt) {
      short8 b = *(const short8*)(Wo + ((nt * 16 + r16) << 7) + s * 32 + kgrp * 8);
      acc[nt] = __builtin_amdgcn_mfma_f32_16x16x32_bf16(a, b, acc[nt], 0, 0, 0);
    }
  }

  __shared__ __align__(16) unsigned short tile[64][DD + 8];
#pragma unroll
  for (int nt = 0; nt < 8; ++nt) {
    int col = nt * 16 + r16;
    float bb = bias[col];
#pragma unroll
    for (int i = 0; i < 4; ++i) {
      int wrow = wave * 16 + kgrp * 4 + i;
      tile[wrow][col] = f2bf(acc[nt][i] + bb);
    }
  }
  __syncthreads();

  // blend with stk, store f to global, write f back to tile
  {
    int orow = tid >> 2, seg = tid & 3;
    int grow = blockrow + orow;
    if (grow < M) {
      float aa = alphas[z], na = 1.f - aa;
      unsigned short* Yp = yf.p[z] + (size_t)grow * DD + seg * 32;
      const unsigned short* sp = stks.p[z] + (size_t)grow * DD + seg * 32;
      unsigned short* tp = &tile[orow][seg * 32];
#pragma unroll
      for (int k = 0; k < 4; ++k) {
        uint4 pv = *(const uint4*)(tp + k * 8);
        uint4 sv = *(const uint4*)(sp + k * 8);
        const unsigned* pw = &pv.x;
        const unsigned* sw = &sv.x;
        uint4 o; unsigned* ow = &o.x;
#pragma unroll
        for (int j = 0; j < 4; ++j)
          ow[j] = pack2(aa * bf_lo(pw[j]) + na * bf_lo(sw[j]),
                        aa * bf_hi(pw[j]) + na * bf_hi(sw[j]));
        *(uint4*)(Yp + k * 8) = o;
        *(uint4*)(tp + k * 8) = o;
      }
    }
  }
  __syncthreads();

  // stage 2: g = f @ Wf; ss += leaky(g + fusion_b) * fq  (guarded rows)
  f32x4 acc2[8];
#pragma unroll
  for (int nt = 0; nt < 8; ++nt)
#pragma unroll
    for (int j = 0; j < 4; ++j) acc2[nt][j] = 0.f;
  const unsigned short* Tp = &tile[wave * 16 + r16][kgrp * 8];
#pragma unroll
  for (int s = 0; s < 4; ++s) {
    short8 a2 = *(const short8*)(Tp + s * 32);
#pragma unroll
    for (int nt = 0; nt < 8; ++nt) {
      short8 b = *(const short8*)(Wf + ((nt * 16 + r16) << 7) + s * 32 + kgrp * 8);
      acc2[nt] = __builtin_amdgcn_mfma_f32_16x16x32_bf16(a2, b, acc2[nt], 0, 0, 0);
    }
  }
  float ss = 0.f;
#pragma unroll
  for (int nt = 0; nt < 8; ++nt) {
    int col = nt * 16 + r16;
    float bb = fusion_b[col];
    float qc = fq[col];
#pragma unroll
    for (int i = 0; i < 4; ++i) {
      int row = rowbase + kgrp * 4 + i;
      if (row < M) {
        float y = acc2[nt][i] + bb;
        float v = y > 0.f ? y : 0.01f * y;
        ss += v * qc;
      }
    }
  }
  __shared__ float red[256];
  red[tid] = ss;
  __syncthreads();
  for (int st = 128; st > 0; st >>= 1) {
    if (tid < st) red[tid] += red[tid + st];
    __syncthreads();
  }
  if (tid == 0) atomicAdd(S + z, red[0]);
}

// ---------------- GCN aggregation: CSR gather, bf16, unroll x8 ----------------
__global__ __launch_bounds__(256) void gather_agg(const int* __restrict__ srcbuf,
                                                  const int* __restrict__ offs,
                                                  const int* __restrict__ deg,
                                                  const float* __restrict__ dinv,
                                                  const unsigned* __restrict__ Bs2,
                                                  const float* __restrict__ bias,
                                                  unsigned* __restrict__ Ab2, int N4) {
  int rn = blockIdx.x * 4 + (threadIdx.x >> 6);
  if (rn >= N4) return;
  int lane = threadIdx.x & 63;
  int st = offs[rn], cnt = deg[rn];
  unsigned u = Bs2[(size_t)rn * 64 + lane];        // self message
  float a0 = bf_lo(u), a1 = bf_hi(u);
  int e = 0;
  for (; e + 8 <= cnt; e += 8) {
    int rr[8];
#pragma unroll
    for (int j = 0; j < 8; ++j) rr[j] = srcbuf[st + e + j];
    unsigned vv[8];
#pragma unroll
    for (int j = 0; j < 8; ++j) vv[j] = Bs2[(size_t)rr[j] * 64 + lane];
#pragma unroll
    for (int j = 0; j < 8; ++j) { a0 += bf_lo(vv[j]); a1 += bf_hi(vv[j]); }
  }
  if (e + 4 <= cnt) {
    int rr[4];
#pragma unroll
    for (int j = 0; j < 4; ++j) rr[j] = srcbuf[st + e + j];
    unsigned vv[4];
#pragma unroll
    for (int j = 0; j < 4; ++j) vv[j] = Bs2[(size_t)rr[j] * 64 + lane];
#pragma unroll
    for (int j = 0; j < 4; ++j) { a0 += bf_lo(vv[j]); a1 += bf_hi(vv[j]); }
    e += 4;
  }
  for (; e < cnt; ++e) {
    unsigned v = Bs2[(size_t)srcbuf[st + e] * 64 + lane];
    a0 += bf_lo(v); a1 += bf_hi(v);
  }
  float dvv = dinv[rn];
  int c = lane * 2;
  Ab2[(size_t)rn * 64 + lane] = pack2(a0 * dvv + bias[c], a1 * dvv + bias[c + 1]);
}

// ---------------- batchnorm ----------------

__global__ void bn_stats(const unsigned* __restrict__ Ab2, float* __restrict__ sums, int N) {
  int r = blockIdx.y;
  int lane = threadIdx.x & 63, grp = threadIdx.x >> 6;
  float s0 = 0.f, q0 = 0.f, s1 = 0.f, q1 = 0.f;
  const unsigned* base = Ab2 + (size_t)r * N * 64;
  for (int n = blockIdx.x * 4 + grp; n < N; n += gridDim.x * 4) {
    unsigned u = base[(size_t)n * 64 + lane];
    float a = bf_lo(u), b = bf_hi(u);
    s0 += a; q0 += a * a; s1 += b; q1 += b * b;
  }
  __shared__ float sh[4][64][4];
  sh[grp][lane][0] = s0; sh[grp][lane][1] = q0; sh[grp][lane][2] = s1; sh[grp][lane][3] = q1;
  __syncthreads();
  if (grp == 0) {
#pragma unroll
    for (int g = 1; g < 4; ++g) {
      s0 += sh[g][lane][0]; q0 += sh[g][lane][1]; s1 += sh[g][lane][2]; q1 += sh[g][lane][3];
    }
    int c0 = lane * 2;
    atomicAdd(sums + (r * DD + c0) * 2, s0);
    atomicAdd(sums + (r * DD + c0) * 2 + 1, q0);
    atomicAdd(sums + (r * DD + c0 + 1) * 2, s1);
    atomicAdd(sums + (r * DD + c0 + 1) * 2 + 1, q1);
  }
}

__global__ void bn_final(const float* __restrict__ sums, const float* __restrict__ gamma,
                         const float* __restrict__ beta, float* __restrict__ ss, int N) {
  int t = threadIdx.x;       // 512 = r*128+c
  int c = t & 127;
  float mu = sums[t * 2] / N;
  float var = sums[t * 2 + 1] / N - mu * mu;
  float sc = gamma[c] * rsqrtf(var + 1e-5f);
  ss[t * 2] = sc;
  ss[t * 2 + 1] = beta[c] - mu * sc;
}

// ---------------- fused attention (per-node: QK^T -> softmax -> PV) ----------------
__global__ void attn_fused(const unsigned short* __restrict__ Q,
                           const unsigned short* __restrict__ K,
                           const unsigned short* __restrict__ V,
                           unsigned* __restrict__ Ob2, int N) {
  int sb = threadIdx.x >> 6;                // 4 nodes / block
  int node = blockIdx.x * 4 + sb;
  int lane = threadIdx.x & 63;
  __shared__ float qs[4][4][132], ks[4][4][132], vs[4][4][132];
  __shared__ float ps[4][64];
  if (node < N) {
    int l = lane >> 4, c8 = (lane & 15) * 8;
    uint4 qv = *(const uint4*)(Q + ((size_t)l * N + node) * DD + c8);
    uint4 kv = *(const uint4*)(K + ((size_t)l * N + node) * DD + c8);
    uint4 vv = *(const uint4*)(V + ((size_t)l * N + node) * DD + c8);
    unsigned qa[4] = {qv.x, qv.y, qv.z, qv.w};
    unsigned ka[4] = {kv.x, kv.y, kv.z, kv.w};
    unsigned va[4] = {vv.x, vv.y, vv.z, vv.w};
#pragma unroll
    for (int j = 0; j < 4; ++j) {
      qs[sb][l][c8 + 2 * j]     = bf_lo(qa[j]);
      qs[sb][l][c8 + 2 * j + 1] = bf_hi(qa[j]);
      ks[sb][l][c8 + 2 * j]     = bf_lo(ka[j]);
      ks[sb][l][c8 + 2 * j + 1] = bf_hi(ka[j]);
      vs[sb][l][c8 + 2 * j]     = bf_lo(va[j]);
      vs[sb][l][c8 + 2 * j + 1] = bf_hi(va[j]);
    }
  }
  __syncthreads();
  if (node < N) {
    int h = lane >> 4, l = (lane >> 2) & 3, m = lane & 3;
    const float* qp = &qs[sb][l][h * 32];
    const float* kp = &ks[sb][m][h * 32];
    float s = 0.f;
#pragma unroll
    for (int k2 = 0; k2 < 32; ++k2) s += qp[k2] * kp[k2];
    s *= 0.17677669529663687f;              // 1/sqrt(32)
    float mx = s;
    mx = fmaxf(mx, __shfl_xor(mx, 1));
    mx = fmaxf(mx, __shfl_xor(mx, 2));
    float e = expf(s - mx);
    float sum = e;
    sum += __shfl_xor(sum, 1);
    sum += __shfl_xor(sum, 2);
    ps[sb][lane] = e / sum;                 // [h][l][m]
  }
  __syncthreads();
  if (node < N) {
    int c0 = lane * 2, h = c0 >> 5;
    const float* pp = &ps[sb][h * 16];
#pragma unroll
    for (int l = 0; l < 4; ++l) {
      float ol = pp[l * 4 + 0] * vs[sb][0][c0] + pp[l * 4 + 1] * vs[sb][1][c0] +
                 pp[l * 4 + 2] * vs[sb][2][c0] + pp[l * 4 + 3] * vs[sb][3][c0];
      float oh = pp[l * 4 + 0] * vs[sb][0][c0 + 1] + pp[l * 4 + 1] * vs[sb][1][c0 + 1] +
                 pp[l * 4 + 2] * vs[sb][2][c0 + 1] + pp[l * 4 + 3] * vs[sb][3][c0 + 1];
      Ob2[((size_t)l * N + node) * 64 + lane] = pack2(ol, oh);
    }
  }
}

// w = softmax([S(f0),S(f1),S(f3),S(f2)]);  coef[l] multiplies f[l]: coef = [w0,w1,w3,w2]
__global__ void wcoef(const float* __restrict__ S, float* __restrict__ coef, int N) {
  if (threadIdx.x == 0) {
    float v0 = S[0] / N, v1 = S[1] / N, v2 = S[3] / N, v3 = S[2] / N;
    float mx = fmaxf(fmaxf(v0, v1), fmaxf(v2, v3));
    float e0 = expf(v0 - mx), e1 = expf(v1 - mx), e2 = expf(v2 - mx), e3 = expf(v3 - mx);
    float inv = 1.f / (e0 + e1 + e2 + e3);
    coef[0] = e0 * inv; coef[1] = e1 * inv; coef[2] = e3 * inv; coef[3] = e2 * inv;
  }
}

__device__ __forceinline__ float bfat(uint2 u, int j) {
  unsigned w = (j < 2) ? u.x : u.y;
  return (j & 1) ? bf_hi(w) : bf_lo(w);
}

// region = sum coef[l]*f[l]; outputs: region, region*rels3[{3,0,1,2}]
__global__ void final_out(const unsigned short* __restrict__ fb, const float* __restrict__ coef,
                          const float* __restrict__ rels3, float* __restrict__ out, int N) {
  size_t NK = (size_t)N * DD;
  size_t i4 = (size_t)blockIdx.x * 256 + threadIdx.x;  // 4-elem groups
  if (i4 >= NK / 4) return;
  size_t g = i4 * 4;
  int c = (int)(g & 127);
  float c0 = coef[0], c1 = coef[1], c2 = coef[2], c3 = coef[3];
  uint2 u0 = *(const uint2*)(fb + g);
  uint2 u1 = *(const uint2*)(fb + NK + g);
  uint2 u2 = *(const uint2*)(fb + 2 * NK + g);
  uint2 u3 = *(const uint2*)(fb + 3 * NK + g);
  float4 reg4, o1, o2, o3, o4;
  float* rp = &reg4.x; float* p1 = &o1.x; float* p2 = &o2.x; float* p3 = &o3.x; float* p4 = &o4.x;
#pragma unroll
  for (int j = 0; j < 4; ++j) {
    float region = c0 * bfat(u0, j) + c1 * bfat(u1, j) + c2 * bfat(u2, j) + c3 * bfat(u3, j);
    rp[j] = region;
    p1[j] = region * rels3[3 * DD + c + j];
    p2[j] = region * rels3[0 * DD + c + j];
    p3[j] = region * rels3[1 * DD + c + j];
    p4[j] = region * rels3[2 * DD + c + j];
  }
  *(float4*)(out + g) = reg4;
  *(float4*)(out + NK + g) = o1;
  *(float4*)(out + 2 * NK + g) = o2;
  *(float4*)(out + 3 * NK + g) = o3;
  *(float4*)(out + 4 * NK + g) = o4;
}

// ---------------- host ----------------

extern "C" void kernel_launch(void* const* d_in, const int* in_sizes, int n_in,
                              void* d_out, int out_size, void* d_ws, size_t ws_size,
                              hipStream_t stream) {
  const float* features  = (const float*)d_in[0];
  const float* rel_emb   = (const float*)d_in[1];
  const int*   edge_idx  = (const int*)d_in[2];
  const float* W_gcn     = (const float*)d_in[3];
  const float* b_gcn     = (const float*)d_in[4];
  const float* bn_gamma  = (const float*)d_in[5];
  const float* bn_beta   = (const float*)d_in[6];
  const float* W_rt      = (const float*)d_in[7];
  const float* b_rt      = (const float*)d_in[8];
  const float* attn_w_in = (const float*)d_in[9];
  const float* attn_b_in = (const float*)d_in[10];
  const float* attn_wout = (const float*)d_in[11];
  const float* attn_bout = (const float*)d_in[12];
  const float* alphas    = (const float*)d_in[13];
  const float* fusion_q  = (const float*)d_in[14];
  const float* fusion_w  = (const float*)d_in[15];
  const float* fusion_b  = (const float*)d_in[16];

  int N = in_sizes[0] / DD;                  // 50000
  int E = in_sizes[2] / (2 * NREL);          // 400000
  size_t NK = (size_t)N * DD;
  int N4 = 4 * N;

  unsigned short* Xb = (unsigned short*)d_ws;            // 4*NK (emb1 / Q / O)
  unsigned short* Bs = Xb + 4 * NK;                      // 4*NK (messages / K / f)
  unsigned short* Ab = Bs + 4 * NK;                      // 4*NK (agg / stack)
  unsigned short* Ub = Ab + 4 * NK;                      // 4*NK (V)
  unsigned short* Fb = Ub + 4 * NK;                      // NK (bf16 features, shared)
  float* dinv  = (float*)(Fb + NK);                      // 4*N
  unsigned short* Wgcnb = (unsigned short*)(dinv + N4);  // 4*16384
  unsigned short* Wab   = Wgcnb + 4 * DD * DD;           // 5*16384
  float* rels  = (float*)(Wab + 5 * DD * DD);            // 4 stages * 512
  float* bnsum = rels + 4 * 512;                         // 1024
  float* bnss  = bnsum + 1024;                           // 1024
  float* S     = bnss + 1024;                            // 4
  float* coef  = S + 4;                                  // 4
  int* deg_i   = (int*)(coef + 4);                       // 4*N
  int* offs    = deg_i + N4;                             // 4*N
  int* cur     = offs + N4;                              // 4*N
  int* bsums   = cur + N4;                               // 1024
  int* srcb    = bsums + 1024;                           // 4*E

  size_t needed = (size_t)((char*)(srcb + 4 * E) - (char*)d_ws);
  if (ws_size < needed) {
    fprintf(stderr, "kernel_launch: ws too small (%zu < %zu)\n", ws_size, needed);
    return;
  }

  int gemmGrid = (N + 63) / 64;
  int scanBlocks = (N4 + 255) / 256;
  int egrid4 = (E + 1023) / 1024;

  // ---- CSR build (edges fixed across layers) ----
  hipMemsetAsync(deg_i, 0, (size_t)N4 * sizeof(int), stream);
  count_deg<<<dim3(egrid4, 4), 256, 0, stream>>>(edge_idx, deg_i, N, E);
  finalize_dinv<<<scanBlocks, 256, 0, stream>>>(deg_i, dinv, N4);
  scan_block<<<scanBlocks, 256, 0, stream>>>(deg_i, offs, bsums, N4);
  scan_sums<<<1, 1024, 0, stream>>>(bsums, scanBlocks);
  scan_add<<<scanBlocks, 256, 0, stream>>>(offs, cur, bsums, N4);
  fill_edges<<<dim3(egrid4, 4), 256, 0, stream>>>(edge_idx, cur, srcb, N, E);

  rels_init<<<1, 512, 0, stream>>>(rel_emb, rels);
  conv_w<<<5 * 16384 / 256, 256, 0, stream>>>(attn_w_in, attn_wout, fusion_w, Wab);
  conv_f2b<<<(int)((NK / 4 + 255) / 256), 256, 0, stream>>>(features, (unsigned*)Fb, NK / 4);

  PtrB4 wz, abIn, resIn;
  OutB4 msgOut, xbOut;
  for (int r = 0; r < 4; ++r) {
    wz.p[r] = Wgcnb + (size_t)r * DD * DD;
    abIn.p[r] = Ab + (size_t)r * NK;
    msgOut.p[r] = Bs + (size_t)r * NK;
    xbOut.p[r] = Xb + (size_t)r * NK;
  }

  // ---- Layer 0 ----
  scale_w_bf<<<256, 256, 0, stream>>>(rels, W_gcn, Wgcnb);
  gemm_msg<<<dim3(gemmGrid, 4), 256, 0, stream>>>(Fb, wz, msgOut, dinv, N);
  gather_agg<<<(N4 + 3) / 4, 256, 0, stream>>>(srcb, offs, deg_i, dinv, (const unsigned*)Bs,
                                               b_gcn, (unsigned*)Ab, N4);
  hipMemsetAsync(bnsum, 0, 1024 * sizeof(float), stream);
  bn_stats<<<dim3(128, 4), 256, 0, stream>>>((const unsigned*)Ab, bnsum, N);
  bn_final<<<1, 512, 0, stream>>>(bnsum, bn_gamma, bn_beta, bnss, N);
  rels_update<<<1, 512, 0, stream>>>(rels, W_rt, b_rt, rels + 512);

  // ---- Layer 1 (fused BN-update, writeback emb1) ----
  scale_w_bf<<<256, 256, 0, stream>>>(rels + 512, W_gcn + (size_t)DD * DD, Wgcnb);
  for (int r = 0; r < 4; ++r) resIn.p[r] = Fb;           // emb0 = features (shared)
  gemm_update<1><<<dim3(gemmGrid, 4), 256, 0, stream>>>(resIn, abIn, wz, xbOut, msgOut,
                                                        bnss, dinv, N);
  gather_agg<<<(N4 + 3) / 4, 256, 0, stream>>>(srcb, offs, deg_i, dinv, (const unsigned*)Bs,
                                               b_gcn + DD, (unsigned*)Ab, N4);
  hipMemsetAsync(bnsum, 0, 1024 * sizeof(float), stream);
  bn_stats<<<dim3(128, 4), 256, 0, stream>>>((const unsigned*)Ab, bnsum, N);
  bn_final<<<1, 512, 0, stream>>>(bnsum, bn_gamma + DD, bn_beta + DD, bnss, N);
  rels_update<<<1, 512, 0, stream>>>(rels + 512, W_rt + (size_t)DD * DD, b_rt + DD, rels + 1024);

  // ---- Layer 2 (fused BN-update, no writeback) ----
  scale_w_bf<<<256, 256, 0, stream>>>(rels + 1024, W_gcn + (size_t)2 * DD * DD, Wgcnb);
  for (int r = 0; r < 4; ++r) resIn.p[r] = Xb + (size_t)r * NK;   // emb1
  gemm_update<0><<<dim3(gemmGrid, 4), 256, 0, stream>>>(resIn, abIn, wz, xbOut, msgOut,
                                                        bnss, dinv, N);
  gather_agg<<<(N4 + 3) / 4, 256, 0, stream>>>(srcb, offs, deg_i, dinv, (const unsigned*)Bs,
                                               b_gcn + 2 * DD, (unsigned*)Ab, N4);
  rels_update<<<1, 512, 0, stream>>>(rels + 1024, W_rt + (size_t)2 * DD * DD, b_rt + 2 * DD,
                                     rels + 1536);
  // Ab = final GCN outputs (stack source). Xb, Bs, Ub free.

  const int pstk[4] = {3, 0, 2, 1};
  PtrB4 stk, fromO;
  OutB4 toQ, toK, toV, toF;
  for (int l = 0; l < 4; ++l) {
    stk.p[l] = Ab + (size_t)pstk[l] * NK;
    toQ.p[l] = Xb + (size_t)l * NK;
    toK.p[l] = Bs + (size_t)l * NK;
    toV.p[l] = Ub + (size_t)l * NK;
    toF.p[l] = Bs + (size_t)l * NK;     // f overwrites K after attn
    fromO.p[l] = Xb + (size_t)l * NK;   // O overwrote Q in-place
  }

  gemm_qkv<<<dim3(gemmGrid, 4), 256, 0, stream>>>(stk, Wab, attn_b_in, toQ, toK, toV, N);
  attn_fused<<<(N + 3) / 4, 256, 0, stream>>>(Xb, Bs, Ub, (unsigned*)Xb, N);
  hipMemsetAsync(S, 0, 4 * sizeof(float), stream);
  gemm_proj<<<dim3(gemmGrid, 4), 256, 0, stream>>>(fromO, Wab + 3 * 16384, Wab + 4 * 16384,
                                                   attn_bout, stk, alphas, fusion_b, fusion_q,
                                                   toF, S, N);
  wcoef<<<1, 64, 0, stream>>>(S, coef, N);
  final_out<<<(int)((NK / 4 + 255) / 256), 256, 0, stream>>>(Bs, coef, rels + 1536,
                                                             (float*)d_out, N);
}

// Round 7
// 1030.700 us; speedup vs baseline: 3.8161x; 1.1303x over previous
//
#include <hip/hip_runtime.h>
#include <cstdio>

#define DD 128
#define NREL 4

using short8 = __attribute__((ext_vector_type(8))) short;
using f32x4  = __attribute__((ext_vector_type(4))) float;

struct PtrB4 { const unsigned short* p[4]; };
struct OutB4 { unsigned short* p[4]; };

// processing-order relation r uses edge_index/rel_emb row (r+3)&3  (perm = [3,0,1,2])
__device__ __forceinline__ int edge_perm(int r) { return (r + 3) & 3; }

__device__ __forceinline__ float bf_lo(unsigned u) { return __uint_as_float(u << 16); }
__device__ __forceinline__ float bf_hi(unsigned u) { return __uint_as_float(u & 0xffff0000u); }
__device__ __forceinline__ float bfe(short s) {
  return __uint_as_float(((unsigned)(unsigned short)s) << 16);
}
__device__ __forceinline__ unsigned short f2bf(float f) {
  unsigned x = __float_as_uint(f);
  unsigned r = (x + 0x7fffu + ((x >> 16) & 1u)) >> 16;
  return (unsigned short)r;
}
__device__ __forceinline__ unsigned pack2(float a, float b) {
  return (unsigned)f2bf(a) | ((unsigned)f2bf(b) << 16);
}

// ---------------- init / weight prep ----------------

__global__ void rels_init(const float* __restrict__ rel_emb, float* __restrict__ rels) {
  int t = threadIdx.x;              // 512 = r*128 + c
  int r = t >> 7, c = t & 127;
  rels[t] = rel_emb[edge_perm(r) * DD + c];
}

__global__ void rels_update(const float* __restrict__ rin, const float* __restrict__ Wrt,
                            const float* __restrict__ brt, float* __restrict__ rout) {
  int t = threadIdx.x;  // 512 = r*128 + j
  int r = t >> 7, j = t & 127;
  float s = brt[j];
  const float* wr = Wrt + j * DD;
  const float* xr = rin + r * DD;
  for (int c = 0; c < DD; ++c) s += xr[c] * wr[c];
  rout[t] = s;
}

// Wsb[r][j][c] = bf16(rels[r][c] * Wg[c][j])  -- MFMA-B layout [n=j][k=c]
__global__ void scale_w_bf(const float* __restrict__ rels_i, const float* __restrict__ Wg,
                           unsigned short* __restrict__ Wsb) {
  int i = blockIdx.x * 256 + threadIdx.x;   // 4*16384
  int r = i >> 14, rem = i & 16383, j = rem >> 7, c = rem & 127;
  Wsb[i] = f2bf(rels_i[r * DD + c] * Wg[c * DD + j]);
}

// Wab = bf16( attn_w_in (3*16384) || attn_wout (16384) || fusion_w (16384) ), all [j][c]
__global__ void conv_w(const float* __restrict__ w_in, const float* __restrict__ w_out,
                       const float* __restrict__ w_fus, unsigned short* __restrict__ Wab) {
  int i = blockIdx.x * 256 + threadIdx.x;   // 5*16384
  float v = (i < 49152) ? w_in[i] : (i < 65536 ? w_out[i - 49152] : w_fus[i - 65536]);
  Wab[i] = f2bf(v);
}

// fp32 -> bf16 single slice
__global__ void conv_f2b(const float* __restrict__ in, unsigned* __restrict__ out2, size_t n4) {
  size_t i = (size_t)blockIdx.x * 256 + threadIdx.x;
  if (i < n4) {
    float4 v = ((const float4*)in)[i];
    out2[i * 2]     = pack2(v.x, v.y);
    out2[i * 2 + 1] = pack2(v.z, v.w);
  }
}

// ---------------- CSR build ----------------

__global__ void count_deg(const int* __restrict__ ei, int* __restrict__ deg, int N, int E) {
  int r = blockIdx.y;
  int base = blockIdx.x * 1024 + threadIdx.x;
  const int* dsts = ei + (size_t)edge_perm(r) * 2 * E + E;
#pragma unroll
  for (int k = 0; k < 4; ++k) {
    int e = base + k * 256;
    if (e < E) atomicAdd(deg + (size_t)r * N + dsts[e], 1);
  }
}

__global__ void finalize_dinv(const int* __restrict__ deg, float* __restrict__ dinv, int total) {
  int i = blockIdx.x * 256 + threadIdx.x;
  if (i < total) dinv[i] = rsqrtf((float)deg[i] + 1.0f);
}

__global__ void scan_block(const int* __restrict__ deg, int* __restrict__ excl,
                           int* __restrict__ bsums, int n) {
  __shared__ int sh[256];
  int i = blockIdx.x * 256 + threadIdx.x;
  int v = (i < n) ? deg[i] : 0;
  sh[threadIdx.x] = v;
  __syncthreads();
  for (int st = 1; st < 256; st <<= 1) {
    int t = (threadIdx.x >= st) ? sh[threadIdx.x - st] : 0;
    __syncthreads();
    sh[threadIdx.x] += t;
    __syncthreads();
  }
  if (i < n) excl[i] = sh[threadIdx.x] - v;
  if (threadIdx.x == 255) bsums[blockIdx.x] = sh[255];
}

__global__ void scan_sums(int* __restrict__ bsums, int nb) {
  __shared__ int sh[1024];
  int v = (threadIdx.x < nb) ? bsums[threadIdx.x] : 0;
  sh[threadIdx.x] = v;
  __syncthreads();
  for (int st = 1; st < 1024; st <<= 1) {
    int t = (threadIdx.x >= st) ? sh[threadIdx.x - st] : 0;
    __syncthreads();
    sh[threadIdx.x] += t;
    __syncthreads();
  }
  if (threadIdx.x < nb) bsums[threadIdx.x] = sh[threadIdx.x] - v;  // exclusive
}

__global__ void scan_add(int* __restrict__ excl, int* __restrict__ cursor,
                         const int* __restrict__ bsums, int n) {
  int i = blockIdx.x * 256 + threadIdx.x;
  if (i < n) {
    int o = excl[i] + bsums[blockIdx.x];
    excl[i] = o;
    cursor[i] = o;
  }
}

// 4 edges/thread: 4 independent atomic-returns in flight
__global__ void fill_edges(const int* __restrict__ ei, int* __restrict__ cursor,
                           int* __restrict__ srcbuf, int N, int E) {
  int r = blockIdx.y;
  int base = blockIdx.x * 1024 + threadIdx.x;
  const int* bp = ei + (size_t)edge_perm(r) * 2 * E;
  int s[4], d[4], pos[4];
#pragma unroll
  for (int k = 0; k < 4; ++k) {
    int e = base + k * 256;
    s[k] = (e < E) ? bp[e] : 0;
    d[k] = (e < E) ? bp[E + e] : 0;
  }
#pragma unroll
  for (int k = 0; k < 4; ++k) {
    int e = base + k * 256;
    if (e < E) pos[k] = atomicAdd(&cursor[r * N + d[k]], 1);
  }
#pragma unroll
  for (int k = 0; k < 4; ++k) {
    int e = base + k * 256;
    if (e < E) srcbuf[pos[k]] = r * N + s[k];
  }
}

// ---------------- weight-stationary MFMA GEMM ----------------
// Block 256 = 4 waves: wave = (rowhalf<<1)|colhalf; each wave: 32 rows x 64 cols.
// B fragments (16 short8 = 64 VGPR) are row-invariant: loaded once before K-loop.
// MODE 0: out bf16 = y * dinv[z*M+row]           (GCN messages)
// MODE 1: out bf16 = y + bias[col]               (Q/K/V)
// MODE 3: out bf16 = alphas[z]*(y+bias) + (1-alphas[z])*stk   (out-proj + blend)
// MODE 2: no store; s += leaky(y+bias[col])*fq[col] -> atomicAdd(S+z)
template <int MODE>
__global__ __launch_bounds__(256) void gemm_ws(PtrB4 xs, PtrB4 wz, OutB4 ys,
                                               const float* __restrict__ bias,
                                               const float* __restrict__ dinv,
                                               const float* __restrict__ fq,
                                               float* __restrict__ S,
                                               PtrB4 stks,
                                               const float* __restrict__ alphas,
                                               int M) {
  int z = blockIdx.y;
  const unsigned short* __restrict__ X = xs.p[z];
  const unsigned short* __restrict__ W = wz.p[z];
  int tid = threadIdx.x;
  int wave = tid >> 6, lane = tid & 63;
  int r16 = lane & 15, kgrp = lane >> 4;
  int rowhalf = wave >> 1, colbase = (wave & 1) * 64;
  int blockrow = blockIdx.x * 64;

  short8 b[4][4];
#pragma unroll
  for (int s = 0; s < 4; ++s)
#pragma unroll
    for (int cn = 0; cn < 4; ++cn)
      b[s][cn] = *(const short8*)(W + ((colbase + cn * 16 + r16) << 7) + s * 32 + kgrp * 8);

  int row0 = blockrow + rowhalf * 32 + r16;
  int r0c = row0 < M ? row0 : M - 1;
  int r1c = row0 + 16 < M ? row0 + 16 : M - 1;
  short8 a[2][4];
#pragma unroll
  for (int s = 0; s < 4; ++s) {
    a[0][s] = *(const short8*)(X + (size_t)r0c * DD + s * 32 + kgrp * 8);
    a[1][s] = *(const short8*)(X + (size_t)r1c * DD + s * 32 + kgrp * 8);
  }

  f32x4 acc[2][4];
#pragma unroll
  for (int rt = 0; rt < 2; ++rt)
#pragma unroll
    for (int cn = 0; cn < 4; ++cn)
#pragma unroll
      for (int j = 0; j < 4; ++j) acc[rt][cn][j] = 0.f;

#pragma unroll
  for (int s = 0; s < 4; ++s)
#pragma unroll
    for (int rt = 0; rt < 2; ++rt)
#pragma unroll
      for (int cn = 0; cn < 4; ++cn)
        acc[rt][cn] = __builtin_amdgcn_mfma_f32_16x16x32_bf16(a[rt][s], b[s][cn], acc[rt][cn], 0, 0, 0);

  // D layout: col = colbase + cn*16 + (lane&15), row = rowhalf*32 + rt*16 + kgrp*4 + i
  __shared__ float red[256];
  if constexpr (MODE == 2) {
    float ss = 0.f;
#pragma unroll
    for (int rt = 0; rt < 2; ++rt)
#pragma unroll
      for (int cn = 0; cn < 4; ++cn) {
        int col = colbase + cn * 16 + r16;
        float bb = bias[col];
        float qc = fq[col];
#pragma unroll
        for (int i = 0; i < 4; ++i) {
          int row = blockrow + rowhalf * 32 + rt * 16 + kgrp * 4 + i;
          if (row < M) {
            float y = acc[rt][cn][i] + bb;
            float v = y > 0.f ? y : 0.01f * y;
            ss += v * qc;
          }
        }
      }
    red[tid] = ss;
    __syncthreads();
    for (int st = 128; st > 0; st >>= 1) {
      if (tid < st) red[tid] += red[tid + st];
      __syncthreads();
    }
    if (tid == 0) atomicAdd(S + z, red[0]);
  } else {
    __shared__ __align__(16) unsigned short tile[64][DD + 8];
    float dv[2][4];
    if constexpr (MODE == 0) {
#pragma unroll
      for (int rt = 0; rt < 2; ++rt)
#pragma unroll
        for (int i = 0; i < 4; ++i) {
          int row = blockrow + rowhalf * 32 + rt * 16 + kgrp * 4 + i;
          dv[rt][i] = dinv[(size_t)z * M + (row < M ? row : 0)];
        }
    }
#pragma unroll
    for (int rt = 0; rt < 2; ++rt)
#pragma unroll
      for (int cn = 0; cn < 4; ++cn) {
        int col = colbase + cn * 16 + r16;
        float bb = (MODE == 1 || MODE == 3) ? bias[col] : 0.f;
#pragma unroll
        for (int i = 0; i < 4; ++i) {
          int wrow = rowhalf * 32 + rt * 16 + kgrp * 4 + i;
          float y = acc[rt][cn][i] + bb;
          if constexpr (MODE == 0) y *= dv[rt][i];
          tile[wrow][col] = f2bf(y);
        }
      }
    __syncthreads();
    int orow = tid >> 2, seg = tid & 3;
    int grow = blockrow + orow;
    if (grow < M) {
      unsigned short* Yp = ys.p[z] + (size_t)grow * DD + seg * 32;
      const unsigned short* tp = &tile[orow][seg * 32];
      if constexpr (MODE == 3) {
        float aa = alphas[z], na = 1.f - aa;
        const unsigned short* sp = stks.p[z] + (size_t)grow * DD + seg * 32;
#pragma unroll
        for (int k = 0; k < 4; ++k) {
          uint4 pv = *(const uint4*)(tp + k * 8);
          uint4 sv = *(const uint4*)(sp + k * 8);
          const unsigned* pw = &pv.x;
          const unsigned* sw = &sv.x;
          uint4 o; unsigned* ow = &o.x;
#pragma unroll
          for (int j = 0; j < 4; ++j)
            ow[j] = pack2(aa * bf_lo(pw[j]) + na * bf_lo(sw[j]),
                          aa * bf_hi(pw[j]) + na * bf_hi(sw[j]));
          *(uint4*)(Yp + k * 8) = o;
        }
      } else {
#pragma unroll
        for (int k = 0; k < 4; ++k)
          *(uint4*)(Yp + k * 8) = *(const uint4*)(tp + k * 8);
      }
    }
  }
}

// Layers 1/2 fused GEMM: e = res + leaky(bn(Ab)); optional writeback; messages = (e@Wz)*dinv
template <int WB>
__global__ __launch_bounds__(256) void gemm_upd(PtrB4 res, PtrB4 abs_, PtrB4 wz,
                                                OutB4 xout, OutB4 ys,
                                                const float* __restrict__ ssx,
                                                const float* __restrict__ dinv, int M) {
  int z = blockIdx.y;
  const unsigned short* __restrict__ R = res.p[z];
  const unsigned short* __restrict__ A = abs_.p[z];
  const unsigned short* __restrict__ W = wz.p[z];
  int tid = threadIdx.x;

  __shared__ float ssc[DD], ssh[DD];
  if (tid < DD) {
    ssc[tid] = ssx[((size_t)z * DD + tid) * 2];
    ssh[tid] = ssx[((size_t)z * DD + tid) * 2 + 1];
  }
  __syncthreads();

  int wave = tid >> 6, lane = tid & 63;
  int r16 = lane & 15, kgrp = lane >> 4;
  int rowhalf = wave >> 1, colbase = (wave & 1) * 64;
  int blockrow = blockIdx.x * 64;

  short8 b[4][4];
#pragma unroll
  for (int s = 0; s < 4; ++s)
#pragma unroll
    for (int cn = 0; cn < 4; ++cn)
      b[s][cn] = *(const short8*)(W + ((colbase + cn * 16 + r16) << 7) + s * 32 + kgrp * 8);

  int row0 = blockrow + rowhalf * 32 + r16;
  int rc[2];
  rc[0] = row0 < M ? row0 : M - 1;
  rc[1] = row0 + 16 < M ? row0 + 16 : M - 1;
  short8 a[2][4];
#pragma unroll
  for (int rt = 0; rt < 2; ++rt)
#pragma unroll
    for (int s = 0; s < 4; ++s) {
      int cbase = s * 32 + kgrp * 8;
      short8 rv = *(const short8*)(R + (size_t)rc[rt] * DD + cbase);
      short8 av = *(const short8*)(A + (size_t)rc[rt] * DD + cbase);
      short8 av2;
#pragma unroll
      for (int j = 0; j < 8; ++j) {
        float x = bfe(av[j]) * ssc[cbase + j] + ssh[cbase + j];
        x = x > 0.f ? x : 0.01f * x;
        av2[j] = (short)f2bf(bfe(rv[j]) + x);
      }
      a[rt][s] = av2;
    }
  if (WB) {
#pragma unroll
    for (int rt = 0; rt < 2; ++rt) {
      int row = row0 + rt * 16;
      if (row < M) {
#pragma unroll
        for (int s = 0; s < 4; ++s)
          *(short8*)(xout.p[z] + (size_t)row * DD + s * 32 + kgrp * 8) = a[rt][s];
      }
    }
  }

  f32x4 acc[2][4];
#pragma unroll
  for (int rt = 0; rt < 2; ++rt)
#pragma unroll
    for (int cn = 0; cn < 4; ++cn)
#pragma unroll
      for (int j = 0; j < 4; ++j) acc[rt][cn][j] = 0.f;
#pragma unroll
  for (int s = 0; s < 4; ++s)
#pragma unroll
    for (int rt = 0; rt < 2; ++rt)
#pragma unroll
      for (int cn = 0; cn < 4; ++cn)
        acc[rt][cn] = __builtin_amdgcn_mfma_f32_16x16x32_bf16(a[rt][s], b[s][cn], acc[rt][cn], 0, 0, 0);

  __shared__ __align__(16) unsigned short tile[64][DD + 8];
  float dv[2][4];
#pragma unroll
  for (int rt = 0; rt < 2; ++rt)
#pragma unroll
    for (int i = 0; i < 4; ++i) {
      int row = blockrow + rowhalf * 32 + rt * 16 + kgrp * 4 + i;
      dv[rt][i] = dinv[(size_t)z * M + (row < M ? row : 0)];
    }
#pragma unroll
  for (int rt = 0; rt < 2; ++rt)
#pragma unroll
    for (int cn = 0; cn < 4; ++cn) {
      int col = colbase + cn * 16 + r16;
#pragma unroll
      for (int i = 0; i < 4; ++i) {
        int wrow = rowhalf * 32 + rt * 16 + kgrp * 4 + i;
        tile[wrow][col] = f2bf(acc[rt][cn][i] * dv[rt][i]);
      }
    }
  __syncthreads();
  int orow = tid >> 2, seg = tid & 3;
  int grow = blockrow + orow;
  if (grow < M) {
    unsigned short* Yp = ys.p[z] + (size_t)grow * DD + seg * 32;
    const unsigned short* tp = &tile[orow][seg * 32];
#pragma unroll
    for (int k = 0; k < 4; ++k)
      *(uint4*)(Yp + k * 8) = *(const uint4*)(tp + k * 8);
  }
}

// ---------------- GCN aggregation: CSR gather, 2 nodes/wave, unroll x8 ----------------
__global__ __launch_bounds__(256) void gather_agg(const int* __restrict__ srcbuf,
                                                  const int* __restrict__ offs,
                                                  const int* __restrict__ deg,
                                                  const float* __restrict__ dinv,
                                                  const uint2* __restrict__ Bs2,
                                                  const float* __restrict__ bias,
                                                  uint2* __restrict__ Ab2, int N4) {
  int rn = blockIdx.x * 8 + (threadIdx.x >> 5);
  if (rn >= N4) return;
  int lane = threadIdx.x & 31;
  int st = offs[rn], cnt = deg[rn];
  uint2 u = Bs2[(size_t)rn * 32 + lane];        // self message
  float a0 = bf_lo(u.x), a1 = bf_hi(u.x), a2 = bf_lo(u.y), a3 = bf_hi(u.y);
  int e = 0;
  for (; e + 8 <= cnt; e += 8) {
    int rr[8];
#pragma unroll
    for (int j = 0; j < 8; ++j) rr[j] = srcbuf[st + e + j];
    uint2 vv[8];
#pragma unroll
    for (int j = 0; j < 8; ++j) vv[j] = Bs2[(size_t)rr[j] * 32 + lane];
#pragma unroll
    for (int j = 0; j < 8; ++j) {
      a0 += bf_lo(vv[j].x); a1 += bf_hi(vv[j].x);
      a2 += bf_lo(vv[j].y); a3 += bf_hi(vv[j].y);
    }
  }
  if (e + 4 <= cnt) {
    int rr[4];
#pragma unroll
    for (int j = 0; j < 4; ++j) rr[j] = srcbuf[st + e + j];
    uint2 vv[4];
#pragma unroll
    for (int j = 0; j < 4; ++j) vv[j] = Bs2[(size_t)rr[j] * 32 + lane];
#pragma unroll
    for (int j = 0; j < 4; ++j) {
      a0 += bf_lo(vv[j].x); a1 += bf_hi(vv[j].x);
      a2 += bf_lo(vv[j].y); a3 += bf_hi(vv[j].y);
    }
    e += 4;
  }
  for (; e < cnt; ++e) {
    uint2 v = Bs2[(size_t)srcbuf[st + e] * 32 + lane];
    a0 += bf_lo(v.x); a1 += bf_hi(v.x); a2 += bf_lo(v.y); a3 += bf_hi(v.y);
  }
  float dvv = dinv[rn];
  int c = lane * 4;
  uint2 o;
  o.x = pack2(a0 * dvv + bias[c],     a1 * dvv + bias[c + 1]);
  o.y = pack2(a2 * dvv + bias[c + 2], a3 * dvv + bias[c + 3]);
  Ab2[(size_t)rn * 32 + lane] = o;
}

// ---------------- batchnorm ----------------

__global__ void bn_stats(const unsigned* __restrict__ Ab2, float* __restrict__ sums, int N) {
  int r = blockIdx.y;
  int lane = threadIdx.x & 63, grp = threadIdx.x >> 6;
  float s0 = 0.f, q0 = 0.f, s1 = 0.f, q1 = 0.f;
  const unsigned* base = Ab2 + (size_t)r * N * 64;
  for (int n = blockIdx.x * 4 + grp; n < N; n += gridDim.x * 4) {
    unsigned u = base[(size_t)n * 64 + lane];
    float a = bf_lo(u), b = bf_hi(u);
    s0 += a; q0 += a * a; s1 += b; q1 += b * b;
  }
  __shared__ float sh[4][64][4];
  sh[grp][lane][0] = s0; sh[grp][lane][1] = q0; sh[grp][lane][2] = s1; sh[grp][lane][3] = q1;
  __syncthreads();
  if (grp == 0) {
#pragma unroll
    for (int g = 1; g < 4; ++g) {
      s0 += sh[g][lane][0]; q0 += sh[g][lane][1]; s1 += sh[g][lane][2]; q1 += sh[g][lane][3];
    }
    int c0 = lane * 2;
    atomicAdd(sums + (r * DD + c0) * 2, s0);
    atomicAdd(sums + (r * DD + c0) * 2 + 1, q0);
    atomicAdd(sums + (r * DD + c0 + 1) * 2, s1);
    atomicAdd(sums + (r * DD + c0 + 1) * 2 + 1, q1);
  }
}

__global__ void bn_final(const float* __restrict__ sums, const float* __restrict__ gamma,
                         const float* __restrict__ beta, float* __restrict__ ss, int N) {
  int t = threadIdx.x;       // 512 = r*128+c
  int c = t & 127;
  float mu = sums[t * 2] / N;
  float var = sums[t * 2 + 1] / N - mu * mu;
  float sc = gamma[c] * rsqrtf(var + 1e-5f);
  ss[t * 2] = sc;
  ss[t * 2 + 1] = beta[c] - mu * sc;
}

// ---------------- fused attention (per-node: QK^T -> softmax -> PV) ----------------
__global__ void attn_fused(const unsigned short* __restrict__ Q,
                           const unsigned short* __restrict__ K,
                           const unsigned short* __restrict__ V,
                           unsigned* __restrict__ Ob2, int N) {
  int sb = threadIdx.x >> 6;                // 4 nodes / block
  int node = blockIdx.x * 4 + sb;
  int lane = threadIdx.x & 63;
  __shared__ float qs[4][4][132], ks[4][4][132], vs[4][4][132];
  __shared__ float ps[4][64];
  if (node < N) {
    int l = lane >> 4, c8 = (lane & 15) * 8;
    uint4 qv = *(const uint4*)(Q + ((size_t)l * N + node) * DD + c8);
    uint4 kv = *(const uint4*)(K + ((size_t)l * N + node) * DD + c8);
    uint4 vv = *(const uint4*)(V + ((size_t)l * N + node) * DD + c8);
    unsigned qa[4] = {qv.x, qv.y, qv.z, qv.w};
    unsigned ka[4] = {kv.x, kv.y, kv.z, kv.w};
    unsigned va[4] = {vv.x, vv.y, vv.z, vv.w};
#pragma unroll
    for (int j = 0; j < 4; ++j) {
      qs[sb][l][c8 + 2 * j]     = bf_lo(qa[j]);
      qs[sb][l][c8 + 2 * j + 1] = bf_hi(qa[j]);
      ks[sb][l][c8 + 2 * j]     = bf_lo(ka[j]);
      ks[sb][l][c8 + 2 * j + 1] = bf_hi(ka[j]);
      vs[sb][l][c8 + 2 * j]     = bf_lo(va[j]);
      vs[sb][l][c8 + 2 * j + 1] = bf_hi(va[j]);
    }
  }
  __syncthreads();
  if (node < N) {
    int h = lane >> 4, l = (lane >> 2) & 3, m = lane & 3;
    const float* qp = &qs[sb][l][h * 32];
    const float* kp = &ks[sb][m][h * 32];
    float s = 0.f;
#pragma unroll
    for (int k2 = 0; k2 < 32; ++k2) s += qp[k2] * kp[k2];
    s *= 0.17677669529663687f;              // 1/sqrt(32)
    float mx = s;
    mx = fmaxf(mx, __shfl_xor(mx, 1));
    mx = fmaxf(mx, __shfl_xor(mx, 2));
    float e = expf(s - mx);
    float sum = e;
    sum += __shfl_xor(sum, 1);
    sum += __shfl_xor(sum, 2);
    ps[sb][lane] = e / sum;                 // [h][l][m]
  }
  __syncthreads();
  if (node < N) {
    int c0 = lane * 2, h = c0 >> 5;
    const float* pp = &ps[sb][h * 16];
#pragma unroll
    for (int l = 0; l < 4; ++l) {
      float ol = pp[l * 4 + 0] * vs[sb][0][c0] + pp[l * 4 + 1] * vs[sb][1][c0] +
                 pp[l * 4 + 2] * vs[sb][2][c0] + pp[l * 4 + 3] * vs[sb][3][c0];
      float oh = pp[l * 4 + 0] * vs[sb][0][c0 + 1] + pp[l * 4 + 1] * vs[sb][1][c0 + 1] +
                 pp[l * 4 + 2] * vs[sb][2][c0 + 1] + pp[l * 4 + 3] * vs[sb][3][c0 + 1];
      Ob2[((size_t)l * N + node) * 64 + lane] = pack2(ol, oh);
    }
  }
}

// w = softmax([S(f0),S(f1),S(f3),S(f2)]);  coef[l] multiplies f[l]: coef = [w0,w1,w3,w2]
__global__ void wcoef(const float* __restrict__ S, float* __restrict__ coef, int N) {
  if (threadIdx.x == 0) {
    float v0 = S[0] / N, v1 = S[1] / N, v2 = S[3] / N, v3 = S[2] / N;
    float mx = fmaxf(fmaxf(v0, v1), fmaxf(v2, v3));
    float e0 = expf(v0 - mx), e1 = expf(v1 - mx), e2 = expf(v2 - mx), e3 = expf(v3 - mx);
    float inv = 1.f / (e0 + e1 + e2 + e3);
    coef[0] = e0 * inv; coef[1] = e1 * inv; coef[2] = e3 * inv; coef[3] = e2 * inv;
  }
}

__device__ __forceinline__ float bfat(uint2 u, int j) {
  unsigned w = (j < 2) ? u.x : u.y;
  return (j & 1) ? bf_hi(w) : bf_lo(w);
}

// region = sum coef[l]*f[l]; outputs: region, region*rels3[{3,0,1,2}]
__global__ void final_out(const unsigned short* __restrict__ fb, const float* __restrict__ coef,
                          const float* __restrict__ rels3, float* __restrict__ out, int N) {
  size_t NK = (size_t)N * DD;
  size_t i4 = (size_t)blockIdx.x * 256 + threadIdx.x;  // 4-elem groups
  if (i4 >= NK / 4) return;
  size_t g = i4 * 4;
  int c = (int)(g & 127);
  float c0 = coef[0], c1 = coef[1], c2 = coef[2], c3 = coef[3];
  uint2 u0 = *(const uint2*)(fb + g);
  uint2 u1 = *(const uint2*)(fb + NK + g);
  uint2 u2 = *(const uint2*)(fb + 2 * NK + g);
  uint2 u3 = *(const uint2*)(fb + 3 * NK + g);
  float4 reg4, o1, o2, o3, o4;
  float* rp = &reg4.x; float* p1 = &o1.x; float* p2 = &o2.x; float* p3 = &o3.x; float* p4 = &o4.x;
#pragma unroll
  for (int j = 0; j < 4; ++j) {
    float region = c0 * bfat(u0, j) + c1 * bfat(u1, j) + c2 * bfat(u2, j) + c3 * bfat(u3, j);
    rp[j] = region;
    p1[j] = region * rels3[3 * DD + c + j];
    p2[j] = region * rels3[0 * DD + c + j];
    p3[j] = region * rels3[1 * DD + c + j];
    p4[j] = region * rels3[2 * DD + c + j];
  }
  *(float4*)(out + g) = reg4;
  *(float4*)(out + NK + g) = o1;
  *(float4*)(out + 2 * NK + g) = o2;
  *(float4*)(out + 3 * NK + g) = o3;
  *(float4*)(out + 4 * NK + g) = o4;
}

// ---------------- host ----------------

extern "C" void kernel_launch(void* const* d_in, const int* in_sizes, int n_in,
                              void* d_out, int out_size, void* d_ws, size_t ws_size,
                              hipStream_t stream) {
  const float* features  = (const float*)d_in[0];
  const float* rel_emb   = (const float*)d_in[1];
  const int*   edge_idx  = (const int*)d_in[2];
  const float* W_gcn     = (const float*)d_in[3];
  const float* b_gcn     = (const float*)d_in[4];
  const float* bn_gamma  = (const float*)d_in[5];
  const float* bn_beta   = (const float*)d_in[6];
  const float* W_rt      = (const float*)d_in[7];
  const float* b_rt      = (const float*)d_in[8];
  const float* attn_w_in = (const float*)d_in[9];
  const float* attn_b_in = (const float*)d_in[10];
  const float* attn_wout = (const float*)d_in[11];
  const float* attn_bout = (const float*)d_in[12];
  const float* alphas    = (const float*)d_in[13];
  const float* fusion_q  = (const float*)d_in[14];
  const float* fusion_w  = (const float*)d_in[15];
  const float* fusion_b  = (const float*)d_in[16];

  int N = in_sizes[0] / DD;                  // 50000
  int E = in_sizes[2] / (2 * NREL);          // 400000
  size_t NK = (size_t)N * DD;
  int N4 = 4 * N;

  unsigned short* Xb = (unsigned short*)d_ws;            // 4*NK (emb1 / Q / O)
  unsigned short* Bs = Xb + 4 * NK;                      // 4*NK (messages / K / f)
  unsigned short* Ab = Bs + 4 * NK;                      // 4*NK (agg / stack)
  unsigned short* Ub = Ab + 4 * NK;                      // 4*NK (V)
  unsigned short* Fb = Ub + 4 * NK;                      // NK (bf16 features, shared)
  float* dinv  = (float*)(Fb + NK);                      // 4*N
  unsigned short* Wgcnb = (unsigned short*)(dinv + N4);  // 4*16384
  unsigned short* Wab   = Wgcnb + 4 * DD * DD;           // 5*16384
  float* rels  = (float*)(Wab + 5 * DD * DD);            // 4 stages * 512
  float* bnsum = rels + 4 * 512;                         // 1024
  float* bnss  = bnsum + 1024;                           // 1024
  float* S     = bnss + 1024;                            // 4
  float* coef  = S + 4;                                  // 4
  int* deg_i   = (int*)(coef + 4);                       // 4*N
  int* offs    = deg_i + N4;                             // 4*N
  int* cur     = offs + N4;                              // 4*N
  int* bsums   = cur + N4;                               // 1024
  int* srcb    = bsums + 1024;                           // 4*E

  size_t needed = (size_t)((char*)(srcb + 4 * E) - (char*)d_ws);
  if (ws_size < needed) {
    fprintf(stderr, "kernel_launch: ws too small (%zu < %zu)\n", ws_size, needed);
    return;
  }

  int gemmGrid = (N + 63) / 64;
  int scanBlocks = (N4 + 255) / 256;
  int egrid4 = (E + 1023) / 1024;

  // ---- CSR build (edges fixed across layers) ----
  hipMemsetAsync(deg_i, 0, (size_t)N4 * sizeof(int), stream);
  count_deg<<<dim3(egrid4, 4), 256, 0, stream>>>(edge_idx, deg_i, N, E);
  finalize_dinv<<<scanBlocks, 256, 0, stream>>>(deg_i, dinv, N4);
  scan_block<<<scanBlocks, 256, 0, stream>>>(deg_i, offs, bsums, N4);
  scan_sums<<<1, 1024, 0, stream>>>(bsums, scanBlocks);
  scan_add<<<scanBlocks, 256, 0, stream>>>(offs, cur, bsums, N4);
  fill_edges<<<dim3(egrid4, 4), 256, 0, stream>>>(edge_idx, cur, srcb, N, E);

  rels_init<<<1, 512, 0, stream>>>(rel_emb, rels);
  conv_w<<<5 * 16384 / 256, 256, 0, stream>>>(attn_w_in, attn_wout, fusion_w, Wab);
  conv_f2b<<<(int)((NK / 4 + 255) / 256), 256, 0, stream>>>(features, (unsigned*)Fb, NK / 4);

  PtrB4 wz, abIn, resIn, dummyP;
  OutB4 msgOut, xbOut, dummyO;
  for (int r = 0; r < 4; ++r) {
    wz.p[r] = Wgcnb + (size_t)r * DD * DD;
    abIn.p[r] = Ab + (size_t)r * NK;
    msgOut.p[r] = Bs + (size_t)r * NK;
    xbOut.p[r] = Xb + (size_t)r * NK;
    dummyP.p[r] = nullptr;
    dummyO.p[r] = nullptr;
  }
  const float* dummy = nullptr;

  // ---- Layer 0 ----
  scale_w_bf<<<256, 256, 0, stream>>>(rels, W_gcn, Wgcnb);
  {
    PtrB4 xs; for (int r = 0; r < 4; ++r) xs.p[r] = Fb;
    gemm_ws<0><<<dim3(gemmGrid, 4), 256, 0, stream>>>(xs, wz, msgOut, dummy, dinv, dummy,
                                                      nullptr, dummyP, dummy, N);
  }
  gather_agg<<<(N4 + 7) / 8, 256, 0, stream>>>(srcb, offs, deg_i, dinv, (const uint2*)Bs,
                                               b_gcn, (uint2*)Ab, N4);
  hipMemsetAsync(bnsum, 0, 1024 * sizeof(float), stream);
  bn_stats<<<dim3(128, 4), 256, 0, stream>>>((const unsigned*)Ab, bnsum, N);
  bn_final<<<1, 512, 0, stream>>>(bnsum, bn_gamma, bn_beta, bnss, N);
  rels_update<<<1, 512, 0, stream>>>(rels, W_rt, b_rt, rels + 512);

  // ---- Layer 1 (fused BN-update, writeback emb1) ----
  scale_w_bf<<<256, 256, 0, stream>>>(rels + 512, W_gcn + (size_t)DD * DD, Wgcnb);
  for (int r = 0; r < 4; ++r) resIn.p[r] = Fb;           // emb0 = features (shared)
  gemm_upd<1><<<dim3(gemmGrid, 4), 256, 0, stream>>>(resIn, abIn, wz, xbOut, msgOut,
                                                     bnss, dinv, N);
  gather_agg<<<(N4 + 7) / 8, 256, 0, stream>>>(srcb, offs, deg_i, dinv, (const uint2*)Bs,
                                               b_gcn + DD, (uint2*)Ab, N4);
  hipMemsetAsync(bnsum, 0, 1024 * sizeof(float), stream);
  bn_stats<<<dim3(128, 4), 256, 0, stream>>>((const unsigned*)Ab, bnsum, N);
  bn_final<<<1, 512, 0, stream>>>(bnsum, bn_gamma + DD, bn_beta + DD, bnss, N);
  rels_update<<<1, 512, 0, stream>>>(rels + 512, W_rt + (size_t)DD * DD, b_rt + DD, rels + 1024);

  // ---- Layer 2 (fused BN-update, no writeback) ----
  scale_w_bf<<<256, 256, 0, stream>>>(rels + 1024, W_gcn + (size_t)2 * DD * DD, Wgcnb);
  for (int r = 0; r < 4; ++r) resIn.p[r] = Xb + (size_t)r * NK;   // emb1
  gemm_upd<0><<<dim3(gemmGrid, 4), 256, 0, stream>>>(resIn, abIn, wz, dummyO, msgOut,
                                                     bnss, dinv, N);
  gather_agg<<<(N4 + 7) / 8, 256, 0, stream>>>(srcb, offs, deg_i, dinv, (const uint2*)Bs,
                                               b_gcn + 2 * DD, (uint2*)Ab, N4);
  rels_update<<<1, 512, 0, stream>>>(rels + 1024, W_rt + (size_t)2 * DD * DD, b_rt + 2 * DD,
                                     rels + 1536);
  // Ab = final GCN outputs (stack source). Xb, Bs, Ub free.

  const int pstk[4] = {3, 0, 2, 1};
  PtrB4 stk, fromO, fromF, w4;
  OutB4 toQ, toK, toV, toF;
  for (int l = 0; l < 4; ++l) {
    stk.p[l] = Ab + (size_t)pstk[l] * NK;
    toQ.p[l] = Xb + (size_t)l * NK;
    toK.p[l] = Bs + (size_t)l * NK;
    toV.p[l] = Ub + (size_t)l * NK;
    toF.p[l] = Bs + (size_t)l * NK;     // f overwrites K after attn
    fromO.p[l] = Xb + (size_t)l * NK;   // O overwrote Q in-place
    fromF.p[l] = Bs + (size_t)l * NK;
  }

  for (int l = 0; l < 4; ++l) w4.p[l] = Wab;                        // Wq
  gemm_ws<1><<<dim3(gemmGrid, 4), 256, 0, stream>>>(stk, w4, toQ, attn_b_in, dummy, dummy,
                                                    nullptr, dummyP, dummy, N);
  for (int l = 0; l < 4; ++l) w4.p[l] = Wab + 16384;                // Wk
  gemm_ws<1><<<dim3(gemmGrid, 4), 256, 0, stream>>>(stk, w4, toK, attn_b_in + DD, dummy, dummy,
                                                    nullptr, dummyP, dummy, N);
  for (int l = 0; l < 4; ++l) w4.p[l] = Wab + 2 * 16384;            // Wv
  gemm_ws<1><<<dim3(gemmGrid, 4), 256, 0, stream>>>(stk, w4, toV, attn_b_in + 2 * DD, dummy,
                                                    dummy, nullptr, dummyP, dummy, N);
  attn_fused<<<(N + 3) / 4, 256, 0, stream>>>(Xb, Bs, Ub, (unsigned*)Xb, N);
  for (int l = 0; l < 4; ++l) w4.p[l] = Wab + 3 * 16384;            // Wo (+blend fused)
  gemm_ws<3><<<dim3(gemmGrid, 4), 256, 0, stream>>>(fromO, w4, toF, attn_bout, dummy, dummy,
                                                    nullptr, stk, alphas, N);
  hipMemsetAsync(S, 0, 4 * sizeof(float), stream);
  for (int l = 0; l < 4; ++l) w4.p[l] = Wab + 4 * 16384;            // Wfus (score fused)
  gemm_ws<2><<<dim3(gemmGrid, 4), 256, 0, stream>>>(fromF, w4, toQ /*unused*/, fusion_b, dummy,
                                                    fusion_q, S, dummyP, dummy, N);
  wcoef<<<1, 64, 0, stream>>>(S, coef, N);
  final_out<<<(int)((NK / 4 + 255) / 256), 256, 0, stream>>>(Bs, coef, rels + 1536,
                                                             (float*)d_out, N);
}